// Round 1
// baseline (705.451 us; speedup 1.0000x reference)
//
#include <hip/hip_runtime.h>

#define S_ 256
#define N_ 384
#define C_ 512
#define H_ 8
#define C3_ 1536
#define R_ (N_*S_)
#define SPLITK 16
#define NPK (N_/SPLITK)   // 24

typedef _Float16 f16;
typedef _Float16 f16x8 __attribute__((ext_vector_type(8)));
typedef float f32x4 __attribute__((ext_vector_type(4)));

#define MFMA16(a,b,c) __builtin_amdgcn_mfma_f32_16x16x32_f16(a,b,c,0,0,0)

// [row][64] f16 tile, 8 granules of 8 f16 (16B); XOR-swizzle granule with row&7
__device__ __forceinline__ int swz_off(int row, int g) {
    return row*64 + (((g) ^ (row & 7)) << 3);
}

__global__ __launch_bounds__(256) void k_prep(const float* __restrict__ Wqkv,
                                              const float* __restrict__ Wout,
                                              f16* __restrict__ Wq16, f16* __restrict__ Wo16) {
    int i = blockIdx.x * 256 + threadIdx.x;
    if (i < C3_ * C_) Wq16[i] = (f16)Wqkv[i];
    if (i < C_ * C_)  Wo16[i] = (f16)Wout[i];
}

// qkv[r][j] = sum_c msa[s][n][c] * Wqkv[j][c] + bqkv[j], r=(n,s), fp16 out
__global__ __launch_bounds__(256) void k_qkv(const float* __restrict__ msa,
                                             const f16* __restrict__ W,
                                             const float* __restrict__ bqkv,
                                             f16* __restrict__ qkv) {
    // XCD-aware swizzle: 9216 blocks, 8 XCDs, 1152 per XCD (exact)
    int wg = (blockIdx.x & 7) * 1152 + (blockIdx.x >> 3);
    int bx = wg / 12, by = wg % 12;
    int n = bx >> 1, s0 = (bx & 1) << 7, j0 = by << 7;
    int tid = threadIdx.x, lane = tid & 63, wid = tid >> 6;
    int wr = (wid >> 1) << 6, wc = (wid & 1) << 6;
    __shared__ f16 As[128 * 64];
    __shared__ f16 Bs[128 * 64];
    f32x4 acc[4][4] = {};
    for (int kt = 0; kt < 8; ++kt) {
        int c0 = kt << 6;
        __syncthreads();
#pragma unroll
        for (int i = 0; i < 4; ++i) {
            int id = tid + (i << 8);
            int row = id >> 3, c8 = id & 7;
            const float* ga = msa + ((s0 + row) * N_ + n) * C_ + c0 + (c8 << 3);
            float4 lo = *(const float4*)ga;
            float4 hi = *(const float4*)(ga + 4);
            f16x8 va;
            va[0]=(f16)lo.x; va[1]=(f16)lo.y; va[2]=(f16)lo.z; va[3]=(f16)lo.w;
            va[4]=(f16)hi.x; va[5]=(f16)hi.y; va[6]=(f16)hi.z; va[7]=(f16)hi.w;
            *(f16x8*)&As[swz_off(row, c8)] = va;
            *(f16x8*)&Bs[swz_off(row, c8)] = *(const f16x8*)(W + (j0 + row) * C_ + c0 + (c8 << 3));
        }
        __syncthreads();
#pragma unroll
        for (int ks = 0; ks < 64; ks += 32) {
            int kg = (ks >> 3) + (lane >> 4);
            f16x8 af[4], bf[4];
#pragma unroll
            for (int m = 0; m < 4; ++m) {
                int row = wr + (m << 4) + (lane & 15);
                af[m] = *(const f16x8*)&As[swz_off(row, kg)];
            }
#pragma unroll
            for (int j = 0; j < 4; ++j) {
                int row = wc + (j << 4) + (lane & 15);
                bf[j] = *(const f16x8*)&Bs[swz_off(row, kg)];
            }
#pragma unroll
            for (int m = 0; m < 4; ++m)
#pragma unroll
                for (int j = 0; j < 4; ++j)
                    acc[m][j] = MFMA16(af[m], bf[j], acc[m][j]);
        }
    }
#pragma unroll
    for (int m = 0; m < 4; ++m) {
        int rloc = wr + (m << 4) + ((lane >> 4) << 2);
#pragma unroll
        for (int j = 0; j < 4; ++j) {
            int jc = j0 + wc + (j << 4) + (lane & 15);
            float bv = bqkv[jc];
#pragma unroll
            for (int q = 0; q < 4; ++q) {
                int r = bx * 128 + rloc + q;
                qkv[r * C3_ + jc] = (f16)(acc[m][j][q] + bv);
            }
        }
    }
}

// partial logits: logP[sk][h][s][t] = sum_{n in chunk, d} q[n,s,h,d]*k[n,t,h,d] (fp32)
__global__ __launch_bounds__(256) void k_logits(const f16* __restrict__ qkv,
                                                float* __restrict__ logP) {
    int b = blockIdx.x;
    int sk = b >> 5, rem = b & 31, h = rem >> 2, sb = (rem >> 1) & 1, tb = rem & 1;
    int s0 = sb << 7, t0 = tb << 7, n0 = sk * NPK;
    int tid = threadIdx.x, lane = tid & 63, wid = tid >> 6;
    int wr = (wid >> 1) << 6, wc = (wid & 1) << 6;
    __shared__ f16 As[128 * 64];
    __shared__ f16 Bs[128 * 64];
    f32x4 acc[4][4] = {};
    for (int ni = 0; ni < NPK; ++ni) {
        int n = n0 + ni;
        __syncthreads();
#pragma unroll
        for (int i = 0; i < 4; ++i) {
            int id = tid + (i << 8);
            int row = id >> 3, c8 = id & 7;
            *(f16x8*)&As[swz_off(row, c8)] =
                *(const f16x8*)(qkv + (n * S_ + s0 + row) * C3_ + h * 64 + (c8 << 3));
            *(f16x8*)&Bs[swz_off(row, c8)] =
                *(const f16x8*)(qkv + (n * S_ + t0 + row) * C3_ + 512 + h * 64 + (c8 << 3));
        }
        __syncthreads();
#pragma unroll
        for (int ks = 0; ks < 64; ks += 32) {
            int kg = (ks >> 3) + (lane >> 4);
            f16x8 af[4], bf[4];
#pragma unroll
            for (int m = 0; m < 4; ++m) {
                int row = wr + (m << 4) + (lane & 15);
                af[m] = *(const f16x8*)&As[swz_off(row, kg)];
            }
#pragma unroll
            for (int j = 0; j < 4; ++j) {
                int row = wc + (j << 4) + (lane & 15);
                bf[j] = *(const f16x8*)&Bs[swz_off(row, kg)];
            }
#pragma unroll
            for (int m = 0; m < 4; ++m)
#pragma unroll
                for (int j = 0; j < 4; ++j)
                    acc[m][j] = MFMA16(af[m], bf[j], acc[m][j]);
        }
    }
#pragma unroll
    for (int m = 0; m < 4; ++m) {
        int rloc = wr + (m << 4) + ((lane >> 4) << 2);
#pragma unroll
        for (int j = 0; j < 4; ++j) {
            int tc = t0 + wc + (j << 4) + (lane & 15);
#pragma unroll
            for (int q = 0; q < 4; ++q) {
                int s = s0 + rloc + q;
                logP[((sk * H_ + h) * S_ + s) * S_ + tc] = acc[m][j][q];
            }
        }
    }
}

__global__ __launch_bounds__(256) void k_softmax(const float* __restrict__ logP,
                                                 const int* __restrict__ mask,
                                                 f16* __restrict__ attn) {
    int hs = blockIdx.x;  // h*256 + s
    int t = threadIdx.x, lane = t & 63, wid = t >> 6;
    float v = 0.f;
#pragma unroll
    for (int sk = 0; sk < SPLITK; ++sk)
        v += logP[(sk * H_ * S_ + hs) * S_ + t];
    v *= 0.125f;
    if (mask[t] == 0) v = -1e9f;
    __shared__ float redm[4], reds[4];
    float m_ = v;
    for (int o = 32; o > 0; o >>= 1) m_ = fmaxf(m_, __shfl_xor(m_, o));
    if (lane == 0) redm[wid] = m_;
    __syncthreads();
    float bm = fmaxf(fmaxf(redm[0], redm[1]), fmaxf(redm[2], redm[3]));
    float e = __expf(v - bm);
    float s_ = e;
    for (int o = 32; o > 0; o >>= 1) s_ += __shfl_xor(s_, o);
    if (lane == 0) reds[wid] = s_;
    __syncthreads();
    float tot = reds[0] + reds[1] + reds[2] + reds[3];
    attn[hs * S_ + t] = (f16)(e / tot);
}

// vT[n][h][d][t] = v[n][t][h][d]
__global__ __launch_bounds__(256) void k_vtrans(const f16* __restrict__ qkv,
                                                f16* __restrict__ vT) {
    int n = blockIdx.x >> 3, h = blockIdx.x & 7;
    int tid = threadIdx.x;
    __shared__ f16 T[64 * 65];
    for (int tb = 0; tb < 4; ++tb) {
        __syncthreads();
#pragma unroll
        for (int i = 0; i < 2; ++i) {
            int id = tid + (i << 8);
            int t = id >> 3, c8 = id & 7;
            f16x8 v = *(const f16x8*)(qkv + (n * S_ + tb * 64 + t) * C3_ + 1024 + h * 64 + (c8 << 3));
#pragma unroll
            for (int e = 0; e < 8; ++e) T[(c8 * 8 + e) * 65 + t] = v[e];
        }
        __syncthreads();
#pragma unroll
        for (int i = 0; i < 2; ++i) {
            int id = tid + (i << 8);
            int d = id >> 3, t8 = id & 7;
            f16x8 w;
#pragma unroll
            for (int e = 0; e < 8; ++e) w[e] = T[d * 65 + t8 * 8 + e];
            *(f16x8*)(vT + ((n * H_ + h) * 64 + d) * S_ + tb * 64 + t8 * 8) = w;
        }
    }
}

// attn_out[n][s][h*64+d] = sum_t attn[h][s][t] * vT[n][h][d][t]
__global__ __launch_bounds__(256) void k_pv(const f16* __restrict__ attn,
                                            const f16* __restrict__ vT,
                                            f16* __restrict__ attn_out) {
    int n = blockIdx.x >> 3, h = blockIdx.x & 7;
    int tid = threadIdx.x, lane = tid & 63, wid = tid >> 6;
    __shared__ f16 As[256 * 32];
    __shared__ f16 Bs[64 * 32];
    f32x4 acc[4][4] = {};
    for (int tt = 0; tt < 8; ++tt) {
        int t0 = tt << 5;
        __syncthreads();
#pragma unroll
        for (int i = 0; i < 4; ++i) {
            int id = tid + (i << 8);
            int sr = id >> 2, c4 = id & 3;
            *(f16x8*)&As[sr * 32 + (c4 << 3)] =
                *(const f16x8*)(attn + (h * S_ + sr) * S_ + t0 + (c4 << 3));
        }
        {
            int d = tid >> 2, c4 = tid & 3;
            *(f16x8*)&Bs[d * 32 + (c4 << 3)] =
                *(const f16x8*)(vT + ((n * H_ + h) * 64 + d) * S_ + t0 + (c4 << 3));
        }
        __syncthreads();
        f16x8 af[4], bf[4];
#pragma unroll
        for (int m = 0; m < 4; ++m)
            af[m] = *(const f16x8*)&As[(wid * 64 + m * 16 + (lane & 15)) * 32 + ((lane >> 4) << 3)];
#pragma unroll
        for (int j = 0; j < 4; ++j)
            bf[j] = *(const f16x8*)&Bs[(j * 16 + (lane & 15)) * 32 + ((lane >> 4) << 3)];
#pragma unroll
        for (int m = 0; m < 4; ++m)
#pragma unroll
            for (int j = 0; j < 4; ++j)
                acc[m][j] = MFMA16(af[m], bf[j], acc[m][j]);
    }
#pragma unroll
    for (int m = 0; m < 4; ++m) {
        int sl = wid * 64 + m * 16 + ((lane >> 4) << 2);
#pragma unroll
        for (int j = 0; j < 4; ++j) {
            int d = j * 16 + (lane & 15);
#pragma unroll
            for (int q = 0; q < 4; ++q)
                attn_out[(n * S_ + sl + q) * C_ + h * 64 + d] = (f16)acc[m][j][q];
        }
    }
}

// y = attn_out @ Wout^T + bout; x = msa + y; LayerNorm(x) -> out[s][n][c]
__global__ __launch_bounds__(512) void k_out_ln(const f16* __restrict__ attn_out,
                                                const f16* __restrict__ Wo,
                                                const float* __restrict__ bout,
                                                const float* __restrict__ msa,
                                                const float* __restrict__ gamma,
                                                const float* __restrict__ beta,
                                                float* __restrict__ out) {
    int r0 = blockIdx.x << 6;
    int n = r0 >> 8, s0 = r0 & 255;
    int tid = threadIdx.x, lane = tid & 63, wid = tid >> 6;
    __shared__ f16 As[64 * 32];
    __shared__ f16 Bs[512 * 32];
    __shared__ float redS[8][64], redQ[8][64], muS[64], rsS[64];
    f32x4 acc[4][4] = {};
    for (int kt = 0; kt < 16; ++kt) {
        int c0 = kt << 5;
        __syncthreads();
        if (tid < 256) {
            int row = tid >> 2, c4 = tid & 3;
            *(f16x8*)&As[row * 32 + (c4 << 3)] =
                *(const f16x8*)(attn_out + (r0 + row) * C_ + c0 + (c4 << 3));
        }
#pragma unroll
        for (int i = 0; i < 4; ++i) {
            int id = tid + (i << 9);
            int row = id >> 2, c4 = id & 3;
            *(f16x8*)&Bs[row * 32 + (c4 << 3)] =
                *(const f16x8*)(Wo + row * C_ + c0 + (c4 << 3));
        }
        __syncthreads();
        f16x8 af[4], bf[4];
#pragma unroll
        for (int m = 0; m < 4; ++m)
            af[m] = *(const f16x8*)&As[((m << 4) + (lane & 15)) * 32 + ((lane >> 4) << 3)];
#pragma unroll
        for (int j = 0; j < 4; ++j)
            bf[j] = *(const f16x8*)&Bs[((wid << 6) + (j << 4) + (lane & 15)) * 32 + ((lane >> 4) << 3)];
#pragma unroll
        for (int m = 0; m < 4; ++m)
#pragma unroll
            for (int j = 0; j < 4; ++j)
                acc[m][j] = MFMA16(af[m], bf[j], acc[m][j]);
    }
    float psum[4][4] = {}, psq[4][4] = {};
#pragma unroll
    for (int m = 0; m < 4; ++m)
#pragma unroll
        for (int j = 0; j < 4; ++j) {
            int c = (wid << 6) + (j << 4) + (lane & 15);
            float bj = bout[c];
#pragma unroll
            for (int q = 0; q < 4; ++q) {
                int rl = (m << 4) + ((lane >> 4) << 2) + q;
                int s = s0 + rl;
                float x = acc[m][j][q] + bj + msa[(s * N_ + n) * C_ + c];
                acc[m][j][q] = x;
                psum[m][q] += x;
                psq[m][q] += x * x;
            }
        }
#pragma unroll
    for (int m = 0; m < 4; ++m)
#pragma unroll
        for (int q = 0; q < 4; ++q)
            for (int o = 1; o < 16; o <<= 1) {
                psum[m][q] += __shfl_xor(psum[m][q], o);
                psq[m][q]  += __shfl_xor(psq[m][q], o);
            }
    if ((lane & 15) == 0) {
#pragma unroll
        for (int m = 0; m < 4; ++m)
#pragma unroll
            for (int q = 0; q < 4; ++q) {
                int rl = (m << 4) + ((lane >> 4) << 2) + q;
                redS[wid][rl] = psum[m][q];
                redQ[wid][rl] = psq[m][q];
            }
    }
    __syncthreads();
    if (tid < 64) {
        float t1 = 0.f, t2 = 0.f;
#pragma unroll
        for (int w = 0; w < 8; ++w) { t1 += redS[w][tid]; t2 += redQ[w][tid]; }
        float mu = t1 * (1.0f / 512.0f);
        float var = t2 * (1.0f / 512.0f) - mu * mu;
        muS[tid] = mu;
        rsS[tid] = rsqrtf(var + 1e-5f);
    }
    __syncthreads();
#pragma unroll
    for (int m = 0; m < 4; ++m)
#pragma unroll
        for (int j = 0; j < 4; ++j) {
            int c = (wid << 6) + (j << 4) + (lane & 15);
            float g = gamma[c], bb = beta[c];
#pragma unroll
            for (int q = 0; q < 4; ++q) {
                int rl = (m << 4) + ((lane >> 4) << 2) + q;
                int s = s0 + rl;
                float y = (acc[m][j][q] - muS[rl]) * rsS[rl] * g + bb;
                out[(s * N_ + n) * C_ + c] = y;
            }
        }
}

extern "C" void kernel_launch(void* const* d_in, const int* in_sizes, int n_in,
                              void* d_out, int out_size, void* d_ws, size_t ws_size,
                              hipStream_t stream) {
    const float* msa   = (const float*)d_in[0];
    const int*   mask  = (const int*)d_in[1];
    const float* Wqkv  = (const float*)d_in[2];
    const float* bqkv  = (const float*)d_in[3];
    const float* Wout  = (const float*)d_in[4];
    const float* bout  = (const float*)d_in[5];
    const float* gamma = (const float*)d_in[6];
    const float* beta  = (const float*)d_in[7];
    float* out = (float*)d_out;
    char* ws = (char*)d_ws;

    f16*   qkv  = (f16*)(ws);                        // 301,989,888 B
    f16*   vT   = (f16*)(ws + 301989888);            // 100,663,296 B
    float* logP = (float*)(ws + 402653184);          //  33,554,432 B
    f16*   attn = (f16*)(ws + 436207616);            //   1,048,576 B
    f16*   Wq16 = (f16*)(ws + 437256192);            //   1,572,864 B
    f16*   Wo16 = (f16*)(ws + 438829056);            //     524,288 B
    f16*   attn_out = qkv;                           // alias: qkv dead after k_vtrans

    k_prep<<<dim3(3072), dim3(256), 0, stream>>>(Wqkv, Wout, Wq16, Wo16);
    k_qkv<<<dim3(9216), dim3(256), 0, stream>>>(msa, Wq16, bqkv, qkv);
    k_logits<<<dim3(512), dim3(256), 0, stream>>>(qkv, logP);
    k_softmax<<<dim3(2048), dim3(256), 0, stream>>>(logP, mask, attn);
    k_vtrans<<<dim3(3072), dim3(256), 0, stream>>>(qkv, vT);
    k_pv<<<dim3(3072), dim3(256), 0, stream>>>(attn, vT, attn_out);
    k_out_ln<<<dim3(1536), dim3(512), 0, stream>>>(attn_out, Wo16, bout, msa, gamma, beta, out);
}

// Round 2
// 667.503 us; speedup vs baseline: 1.0569x; 1.0569x over previous
//
#include <hip/hip_runtime.h>

#define S_ 256
#define N_ 384
#define C_ 512
#define H_ 8
#define R_ (N_*S_)
#define SPLITK 16
#define NPK (N_/SPLITK)   // 24

typedef _Float16 f16;
typedef _Float16 f16x8 __attribute__((ext_vector_type(8)));
typedef _Float16 f16x4 __attribute__((ext_vector_type(4)));
typedef float f32x4 __attribute__((ext_vector_type(4)));

#define MFMA16(a,b,c) __builtin_amdgcn_mfma_f32_16x16x32_f16(a,b,c,0,0,0)

typedef __attribute__((address_space(3))) unsigned int as3_u32;
typedef __attribute__((address_space(1))) const unsigned int as1_u32;

// async global->LDS, 16B per lane; l must be the wave-uniform base
__device__ __forceinline__ void gl_lds16(const void* g, void* l) {
    __builtin_amdgcn_global_load_lds((as1_u32*)(unsigned long long)g,
                                     (as3_u32*)(unsigned long long)l, 16, 0, 0);
}

// [row][64] f16 tile; granule (8 f16 = 16B) XOR-swizzled with row&7
__device__ __forceinline__ int swz_off(int row, int g) {
    return row*64 + (((g) ^ (row & 7)) << 3);
}

__global__ __launch_bounds__(256) void k_prep(const float* __restrict__ Wqkv,
                                              const float* __restrict__ Wout,
                                              f16* __restrict__ Wq16, f16* __restrict__ Wo16) {
    int i = blockIdx.x * 256 + threadIdx.x;
    if (i < 1536 * C_) Wq16[i] = (f16)Wqkv[i];
    if (i < C_ * C_)   Wo16[i] = (f16)Wout[i];
}

// msaT[r=(n*256+s)][c] = (f16)msa[s][n][c]
__global__ __launch_bounds__(256) void k_cast(const float* __restrict__ msa,
                                              f16* __restrict__ msaT) {
    int t = blockIdx.x * 256 + threadIdx.x;     // 6.29M threads, 8 elems each
    int r = t >> 6, cg = t & 63;
    int n = r >> 8, s = r & 255;
    const float* src = msa + (s * N_ + n) * C_ + (cg << 3);
    float4 lo = *(const float4*)src;
    float4 hi = *(const float4*)(src + 4);
    f16x8 v;
    v[0]=(f16)lo.x; v[1]=(f16)lo.y; v[2]=(f16)lo.z; v[3]=(f16)lo.w;
    v[4]=(f16)hi.x; v[5]=(f16)hi.y; v[6]=(f16)hi.z; v[7]=(f16)hi.w;
    *(f16x8*)(msaT + r * C_ + (cg << 3)) = v;
}

// qk[r][j](j<1024: q|k) and vT[n][h][d][t] from msaT @ Wqkv^T + bqkv
__global__ __launch_bounds__(256) void k_qkv(const f16* __restrict__ msaT,
                                             const f16* __restrict__ W,
                                             const float* __restrict__ bqkv,
                                             f16* __restrict__ qk,
                                             f16* __restrict__ vT) {
    int wg = (blockIdx.x & 7) * 1152 + (blockIdx.x >> 3);   // 9216 = 8*1152 exact
    int bx = wg / 12, by = wg % 12;
    int j0 = by << 7;
    int tid = threadIdx.x, lane = tid & 63, wid = tid >> 6;
    int wr = (wid >> 1) << 6, wc = (wid & 1) << 6;
    __shared__ f16 As[128 * 64];
    __shared__ f16 Bs[128 * 64];
    const f16* Abase = msaT + (bx << 7) * C_;
    const f16* Bbase = W + j0 * C_;
    f32x4 acc[4][4] = {};
    for (int kt = 0; kt < 8; ++kt) {
        int c0 = kt << 6;
        __syncthreads();
#pragma unroll
        for (int i = 0; i < 4; ++i) {
            int id = (i << 8) + tid;
            int row = id >> 3, g = (id & 7) ^ (row & 7);   // inverse-swizzled source
            int lofs = ((i << 8) + (wid << 6)) << 4;       // wave-uniform LDS byte base
            gl_lds16(Abase + row * C_ + c0 + (g << 3), (char*)As + lofs);
            gl_lds16(Bbase + row * C_ + c0 + (g << 3), (char*)Bs + lofs);
        }
        __syncthreads();
#pragma unroll
        for (int ks = 0; ks < 64; ks += 32) {
            int kg = (ks >> 3) + (lane >> 4);
            f16x8 af[4], bf[4];
#pragma unroll
            for (int m = 0; m < 4; ++m)
                af[m] = *(const f16x8*)&As[swz_off(wr + (m << 4) + (lane & 15), kg)];
#pragma unroll
            for (int j = 0; j < 4; ++j)
                bf[j] = *(const f16x8*)&Bs[swz_off(wc + (j << 4) + (lane & 15), kg)];
#pragma unroll
            for (int m = 0; m < 4; ++m)
#pragma unroll
                for (int j = 0; j < 4; ++j)
                    acc[m][j] = MFMA16(af[m], bf[j], acc[m][j]);
        }
    }
#pragma unroll
    for (int m = 0; m < 4; ++m) {
        int rloc = wr + (m << 4) + ((lane >> 4) << 2);
        int r0 = (bx << 7) + rloc;
        if (by < 8) {
#pragma unroll
            for (int j = 0; j < 4; ++j) {
                int jc = j0 + wc + (j << 4) + (lane & 15);
                float bv = bqkv[jc];
#pragma unroll
                for (int q = 0; q < 4; ++q)
                    qk[(r0 + q) * 1024 + jc] = (f16)(acc[m][j][q] + bv);
            }
        } else {
            int n = bx >> 1, sBase = ((bx & 1) << 7) + rloc;
#pragma unroll
            for (int j = 0; j < 4; ++j) {
                int jl = (j0 - 1024) + wc + (j << 4) + (lane & 15);  // 0..511
                float bv = bqkv[1024 + jl];
                f16x4 vv;
#pragma unroll
                for (int q = 0; q < 4; ++q) vv[q] = (f16)(acc[m][j][q] + bv);
                *(f16x4*)(vT + ((n * H_ + (jl >> 6)) * 64 + (jl & 63)) * S_ + sBase) = vv;
            }
        }
    }
}

// partial logits: logP[sk][h][s][t] = sum_{n in chunk, d} q[n,s,h,d]*k[n,t,h,d]
__global__ __launch_bounds__(256) void k_logits(const f16* __restrict__ qk,
                                                float* __restrict__ logP) {
    int wg = (blockIdx.x & 7) * 64 + (blockIdx.x >> 3);     // 512 = 8*64 exact
    int sk = wg >> 5, rem = wg & 31, h = rem >> 2, sb = (rem >> 1) & 1, tb = rem & 1;
    int s0 = sb << 7, t0 = tb << 7, n0 = sk * NPK;
    int tid = threadIdx.x, lane = tid & 63, wid = tid >> 6;
    int wr = (wid >> 1) << 6, wc = (wid & 1) << 6;
    __shared__ f16 As[128 * 64];
    __shared__ f16 Bs[128 * 64];
    f32x4 acc[4][4] = {};
    for (int ni = 0; ni < NPK; ++ni) {
        int n = n0 + ni;
        const f16* Abase = qk + (n * S_ + s0) * 1024 + (h << 6);
        const f16* Bbase = qk + (n * S_ + t0) * 1024 + 512 + (h << 6);
        __syncthreads();
#pragma unroll
        for (int i = 0; i < 4; ++i) {
            int id = (i << 8) + tid;
            int row = id >> 3, g = (id & 7) ^ (row & 7);
            int lofs = ((i << 8) + (wid << 6)) << 4;
            gl_lds16(Abase + row * 1024 + (g << 3), (char*)As + lofs);
            gl_lds16(Bbase + row * 1024 + (g << 3), (char*)Bs + lofs);
        }
        __syncthreads();
#pragma unroll
        for (int ks = 0; ks < 64; ks += 32) {
            int kg = (ks >> 3) + (lane >> 4);
            f16x8 af[4], bf[4];
#pragma unroll
            for (int m = 0; m < 4; ++m)
                af[m] = *(const f16x8*)&As[swz_off(wr + (m << 4) + (lane & 15), kg)];
#pragma unroll
            for (int j = 0; j < 4; ++j)
                bf[j] = *(const f16x8*)&Bs[swz_off(wc + (j << 4) + (lane & 15), kg)];
#pragma unroll
            for (int m = 0; m < 4; ++m)
#pragma unroll
                for (int j = 0; j < 4; ++j)
                    acc[m][j] = MFMA16(af[m], bf[j], acc[m][j]);
        }
    }
#pragma unroll
    for (int m = 0; m < 4; ++m) {
        int rloc = wr + (m << 4) + ((lane >> 4) << 2);
#pragma unroll
        for (int j = 0; j < 4; ++j) {
            int tc = t0 + wc + (j << 4) + (lane & 15);
#pragma unroll
            for (int q = 0; q < 4; ++q)
                logP[((sk * H_ + h) * S_ + s0 + rloc + q) * S_ + tc] = acc[m][j][q];
        }
    }
}

__global__ __launch_bounds__(256) void k_softmax(const float* __restrict__ logP,
                                                 const int* __restrict__ mask,
                                                 f16* __restrict__ attn) {
    int hs = blockIdx.x;  // h*256 + s
    int t = threadIdx.x, lane = t & 63, wid = t >> 6;
    float v = 0.f;
#pragma unroll
    for (int sk = 0; sk < SPLITK; ++sk)
        v += logP[(sk * H_ * S_ + hs) * S_ + t];
    v *= 0.125f;
    if (mask[t] == 0) v = -1e9f;
    __shared__ float redm[4], reds[4];
    float m_ = v;
    for (int o = 32; o > 0; o >>= 1) m_ = fmaxf(m_, __shfl_xor(m_, o));
    if (lane == 0) redm[wid] = m_;
    __syncthreads();
    float bm = fmaxf(fmaxf(redm[0], redm[1]), fmaxf(redm[2], redm[3]));
    float e = __expf(v - bm);
    float s_ = e;
    for (int o = 32; o > 0; o >>= 1) s_ += __shfl_xor(s_, o);
    if (lane == 0) reds[wid] = s_;
    __syncthreads();
    float tot = reds[0] + reds[1] + reds[2] + reds[3];
    attn[hs * S_ + t] = (f16)(e / tot);
}

// attn_out[n][s][h*64+d] = sum_t attn[h][s][t] * vT[n][h][d][t]
__global__ __launch_bounds__(256) void k_pv(const f16* __restrict__ attn,
                                            const f16* __restrict__ vT,
                                            f16* __restrict__ attn_out) {
    int n = blockIdx.x >> 3, h = blockIdx.x & 7;
    int tid = threadIdx.x, lane = tid & 63, wid = tid >> 6;
    __shared__ f16 As[256 * 32];
    __shared__ f16 Bs[64 * 32];
    f32x4 acc[4][4] = {};
    for (int tt = 0; tt < 8; ++tt) {
        int t0 = tt << 5;
        __syncthreads();
#pragma unroll
        for (int i = 0; i < 4; ++i) {
            int id = tid + (i << 8);
            int sr = id >> 2, c4 = id & 3;
            *(f16x8*)&As[sr * 32 + (c4 << 3)] =
                *(const f16x8*)(attn + (h * S_ + sr) * S_ + t0 + (c4 << 3));
        }
        {
            int d = tid >> 2, c4 = tid & 3;
            *(f16x8*)&Bs[d * 32 + (c4 << 3)] =
                *(const f16x8*)(vT + ((n * H_ + h) * 64 + d) * S_ + t0 + (c4 << 3));
        }
        __syncthreads();
        f16x8 af[4], bf[4];
#pragma unroll
        for (int m = 0; m < 4; ++m)
            af[m] = *(const f16x8*)&As[(wid * 64 + m * 16 + (lane & 15)) * 32 + ((lane >> 4) << 3)];
#pragma unroll
        for (int j = 0; j < 4; ++j)
            bf[j] = *(const f16x8*)&Bs[(j * 16 + (lane & 15)) * 32 + ((lane >> 4) << 3)];
#pragma unroll
        for (int m = 0; m < 4; ++m)
#pragma unroll
            for (int j = 0; j < 4; ++j)
                acc[m][j] = MFMA16(af[m], bf[j], acc[m][j]);
    }
#pragma unroll
    for (int m = 0; m < 4; ++m) {
        int sl = wid * 64 + m * 16 + ((lane >> 4) << 2);
#pragma unroll
        for (int j = 0; j < 4; ++j) {
            int d = j * 16 + (lane & 15);
#pragma unroll
            for (int q = 0; q < 4; ++q)
                attn_out[(n * S_ + sl + q) * C_ + h * 64 + d] = (f16)acc[m][j][q];
        }
    }
}

// y = attn_out @ Wout^T + bout; x = msaT + y; LayerNorm(x) -> out[s][n][c]
__global__ __launch_bounds__(512) void k_out_ln(const f16* __restrict__ attn_out,
                                                const f16* __restrict__ Wo,
                                                const float* __restrict__ bout,
                                                const f16* __restrict__ msaT,
                                                const float* __restrict__ gamma,
                                                const float* __restrict__ beta,
                                                float* __restrict__ out) {
    int r0 = blockIdx.x << 6;
    int n = r0 >> 8, s0 = r0 & 255;
    int tid = threadIdx.x, lane = tid & 63, wid = tid >> 6;
    __shared__ f16 As[64 * 32];
    __shared__ f16 Bs[512 * 32];
    __shared__ float redS[8][64], redQ[8][64], muS[64], rsS[64];
    f32x4 acc[4][4] = {};
    for (int kt = 0; kt < 16; ++kt) {
        int c0 = kt << 5;
        __syncthreads();
        if (tid < 256) {
            int row = tid >> 2, c4 = tid & 3;
            *(f16x8*)&As[row * 32 + (c4 << 3)] =
                *(const f16x8*)(attn_out + (r0 + row) * C_ + c0 + (c4 << 3));
        }
#pragma unroll
        for (int i = 0; i < 4; ++i) {
            int id = tid + (i << 9);
            int row = id >> 2, c4 = id & 3;
            *(f16x8*)&Bs[row * 32 + (c4 << 3)] =
                *(const f16x8*)(Wo + row * C_ + c0 + (c4 << 3));
        }
        __syncthreads();
        f16x8 af[4], bf[4];
#pragma unroll
        for (int m = 0; m < 4; ++m)
            af[m] = *(const f16x8*)&As[((m << 4) + (lane & 15)) * 32 + ((lane >> 4) << 3)];
#pragma unroll
        for (int j = 0; j < 4; ++j)
            bf[j] = *(const f16x8*)&Bs[((wid << 6) + (j << 4) + (lane & 15)) * 32 + ((lane >> 4) << 3)];
#pragma unroll
        for (int m = 0; m < 4; ++m)
#pragma unroll
            for (int j = 0; j < 4; ++j)
                acc[m][j] = MFMA16(af[m], bf[j], acc[m][j]);
    }
    float psum[4][4] = {}, psq[4][4] = {};
#pragma unroll
    for (int m = 0; m < 4; ++m)
#pragma unroll
        for (int j = 0; j < 4; ++j) {
            int c = (wid << 6) + (j << 4) + (lane & 15);
            float bj = bout[c];
#pragma unroll
            for (int q = 0; q < 4; ++q) {
                int rl = (m << 4) + ((lane >> 4) << 2) + q;
                float x = acc[m][j][q] + bj + (float)msaT[(r0 + rl) * C_ + c];
                acc[m][j][q] = x;
                psum[m][q] += x;
                psq[m][q] += x * x;
            }
        }
#pragma unroll
    for (int m = 0; m < 4; ++m)
#pragma unroll
        for (int q = 0; q < 4; ++q)
            for (int o = 1; o < 16; o <<= 1) {
                psum[m][q] += __shfl_xor(psum[m][q], o);
                psq[m][q]  += __shfl_xor(psq[m][q], o);
            }
    if ((lane & 15) == 0) {
#pragma unroll
        for (int m = 0; m < 4; ++m)
#pragma unroll
            for (int q = 0; q < 4; ++q) {
                int rl = (m << 4) + ((lane >> 4) << 2) + q;
                redS[wid][rl] = psum[m][q];
                redQ[wid][rl] = psq[m][q];
            }
    }
    __syncthreads();
    if (tid < 64) {
        float t1 = 0.f, t2 = 0.f;
#pragma unroll
        for (int w = 0; w < 8; ++w) { t1 += redS[w][tid]; t2 += redQ[w][tid]; }
        float mu = t1 * (1.0f / 512.0f);
        float var = t2 * (1.0f / 512.0f) - mu * mu;
        muS[tid] = mu;
        rsS[tid] = rsqrtf(var + 1e-5f);
    }
    __syncthreads();
#pragma unroll
    for (int m = 0; m < 4; ++m)
#pragma unroll
        for (int j = 0; j < 4; ++j) {
            int c = (wid << 6) + (j << 4) + (lane & 15);
            float g = gamma[c], bb = beta[c];
#pragma unroll
            for (int q = 0; q < 4; ++q) {
                int rl = (m << 4) + ((lane >> 4) << 2) + q;
                int s = s0 + rl;
                float y = (acc[m][j][q] - muS[rl]) * rsS[rl] * g + bb;
                out[(s * N_ + n) * C_ + c] = y;
            }
        }
}

extern "C" void kernel_launch(void* const* d_in, const int* in_sizes, int n_in,
                              void* d_out, int out_size, void* d_ws, size_t ws_size,
                              hipStream_t stream) {
    const float* msa   = (const float*)d_in[0];
    const int*   mask  = (const int*)d_in[1];
    const float* Wqkv  = (const float*)d_in[2];
    const float* bqkv  = (const float*)d_in[3];
    const float* Wout  = (const float*)d_in[4];
    const float* bout  = (const float*)d_in[5];
    const float* gamma = (const float*)d_in[6];
    const float* beta  = (const float*)d_in[7];
    float* out = (float*)d_out;
    char* ws = (char*)d_ws;

    f16*   qk   = (f16*)(ws);                        // 201,326,592 B
    f16*   vT   = (f16*)(ws + 201326592);            // 100,663,296 B
    f16*   msaT = (f16*)(ws + 301989888);            // 100,663,296 B
    float* logP = (float*)(ws + 402653184);          //  33,554,432 B
    f16*   attn = (f16*)(ws + 436207616);            //   1,048,576 B
    f16*   Wq16 = (f16*)(ws + 437256192);            //   1,572,864 B
    f16*   Wo16 = (f16*)(ws + 438829056);            //     524,288 B
    f16*   attn_out = qk;                            // alias: q/k dead after k_logits

    k_prep<<<dim3(3072), dim3(256), 0, stream>>>(Wqkv, Wout, Wq16, Wo16);
    k_cast<<<dim3(24576), dim3(256), 0, stream>>>(msa, msaT);
    k_qkv<<<dim3(9216), dim3(256), 0, stream>>>(msaT, Wq16, bqkv, qk, vT);
    k_logits<<<dim3(512), dim3(256), 0, stream>>>(qk, logP);
    k_softmax<<<dim3(2048), dim3(256), 0, stream>>>(logP, mask, attn);
    k_pv<<<dim3(3072), dim3(256), 0, stream>>>(attn, vT, attn_out);
    k_out_ln<<<dim3(1536), dim3(512), 0, stream>>>(attn_out, Wo16, bout, msaT, gamma, beta, out);
}

// Round 4
// 635.712 us; speedup vs baseline: 1.1097x; 1.0500x over previous
//
#include <hip/hip_runtime.h>

#define S_ 256
#define N_ 384
#define C_ 512
#define H_ 8
#define R_ (N_*S_)
#define SPLITK 16
#define NPK (N_/SPLITK)   // 24

typedef _Float16 f16;
typedef _Float16 f16x8 __attribute__((ext_vector_type(8)));
typedef _Float16 f16x4 __attribute__((ext_vector_type(4)));
typedef float f32x4 __attribute__((ext_vector_type(4)));

#define MFMA16(a,b,c) __builtin_amdgcn_mfma_f32_16x16x32_f16(a,b,c,0,0,0)

typedef __attribute__((address_space(3))) unsigned int as3_u32;
typedef __attribute__((address_space(1))) const unsigned int as1_u32;

// async global->LDS, 16B per lane; l must be the wave-uniform base
__device__ __forceinline__ void gl_lds16(const void* g, void* l) {
    __builtin_amdgcn_global_load_lds((as1_u32*)(unsigned long long)g,
                                     (as3_u32*)(unsigned long long)l, 16, 0, 0);
}

// Stage one [128][32] f16 tile pair (A,B) into LDS, linear dest, source
// pre-swizzled with involution g ^= (row>>1)&3 (rule #21).
__device__ __forceinline__ void stage_tile(const f16* __restrict__ Ab,
                                           const f16* __restrict__ Bb,
                                           int stride, f16* As_, f16* Bs_,
                                           int tid, int wid) {
#pragma unroll
    for (int i = 0; i < 2; ++i) {
        int id = (i << 8) + tid;
        int row = id >> 2;
        int g = (id & 3) ^ ((row >> 1) & 3);
        int lofs = ((i << 8) + (wid << 6)) << 4;   // wave-uniform LDS byte base
        gl_lds16(Ab + row * stride + (g << 3), (char*)As_ + lofs);
        gl_lds16(Bb + row * stride + (g << 3), (char*)Bs_ + lofs);
    }
}

// one K=32 MFMA step from a [128][32] swizzled LDS tile pair
__device__ __forceinline__ void frag_mma(const f16* As_, const f16* Bs_,
                                         int lane, int wr, int wc, f32x4 acc[4][4]) {
    int kg = lane >> 4;
    f16x8 af[4], bf[4];
#pragma unroll
    for (int m = 0; m < 4; ++m) {
        int row = wr + (m << 4) + (lane & 15);
        af[m] = *(const f16x8*)&As_[row * 32 + ((kg ^ ((row >> 1) & 3)) << 3)];
    }
#pragma unroll
    for (int j = 0; j < 4; ++j) {
        int row = wc + (j << 4) + (lane & 15);
        bf[j] = *(const f16x8*)&Bs_[row * 32 + ((kg ^ ((row >> 1) & 3)) << 3)];
    }
#pragma unroll
    for (int m = 0; m < 4; ++m)
#pragma unroll
        for (int j = 0; j < 4; ++j)
            acc[m][j] = MFMA16(af[m], bf[j], acc[m][j]);
}

__global__ __launch_bounds__(256) void k_prep(const float* __restrict__ Wqkv,
                                              const float* __restrict__ Wout,
                                              f16* __restrict__ Wq16, f16* __restrict__ Wo16) {
    int i = blockIdx.x * 256 + threadIdx.x;
    if (i < 1536 * C_) Wq16[i] = (f16)Wqkv[i];
    if (i < C_ * C_)   Wo16[i] = (f16)Wout[i];
}

// msaT[r=(n*256+s)][c] = (f16)msa[s][n][c]
__global__ __launch_bounds__(256) void k_cast(const float* __restrict__ msa,
                                              f16* __restrict__ msaT) {
    int t = blockIdx.x * 256 + threadIdx.x;
    int r = t >> 6, cg = t & 63;
    int n = r >> 8, s = r & 255;
    const float* src = msa + (s * N_ + n) * C_ + (cg << 3);
    float4 lo = *(const float4*)src;
    float4 hi = *(const float4*)(src + 4);
    f16x8 v;
    v[0]=(f16)lo.x; v[1]=(f16)lo.y; v[2]=(f16)lo.z; v[3]=(f16)lo.w;
    v[4]=(f16)hi.x; v[5]=(f16)hi.y; v[6]=(f16)hi.z; v[7]=(f16)hi.w;
    *(f16x8*)(msaT + r * C_ + (cg << 3)) = v;
}

// qk[r][j](j<1024: q|k) and vT[n][h][d][t] from msaT @ Wqkv^T + bqkv
// BK=32 double-buffered: STAGE(next) overlaps frag_mma(cur); one
// __syncthreads() per iteration provides vmcnt(0)+lgkmcnt(0)+barrier
// (= the T3 recipe's end-of-iter fence) with zero race surface.
__global__ __launch_bounds__(256) void k_qkv(const f16* __restrict__ msaT,
                                             const f16* __restrict__ W,
                                             const float* __restrict__ bqkv,
                                             f16* __restrict__ qk,
                                             f16* __restrict__ vT) {
    int wg = (blockIdx.x & 7) * 1152 + (blockIdx.x >> 3);   // 9216 = 8*1152 exact
    int bx = wg / 12, by = wg % 12;
    int j0 = by << 7;
    int tid = threadIdx.x, lane = tid & 63, wid = tid >> 6;
    int wr = (wid >> 1) << 6, wc = (wid & 1) << 6;
    __shared__ f16 As[2][128 * 32];
    __shared__ f16 Bs[2][128 * 32];
    const f16* Abase = msaT + (bx << 7) * C_;
    const f16* Bbase = W + j0 * C_;
    f32x4 acc[4][4] = {};
    stage_tile(Abase, Bbase, C_, As[0], Bs[0], tid, wid);
    __syncthreads();
    for (int t = 0; t < 16; ++t) {
        int cur = t & 1;
        if (t < 15)
            stage_tile(Abase + ((t + 1) << 5), Bbase + ((t + 1) << 5), C_,
                       As[cur ^ 1], Bs[cur ^ 1], tid, wid);
        frag_mma(As[cur], Bs[cur], lane, wr, wc, acc);
        __syncthreads();
    }
#pragma unroll
    for (int m = 0; m < 4; ++m) {
        int rloc = wr + (m << 4) + ((lane >> 4) << 2);
        int r0 = (bx << 7) + rloc;
        if (by < 8) {
#pragma unroll
            for (int j = 0; j < 4; ++j) {
                int jc = j0 + wc + (j << 4) + (lane & 15);
                float bv = bqkv[jc];
#pragma unroll
                for (int q = 0; q < 4; ++q)
                    qk[(r0 + q) * 1024 + jc] = (f16)(acc[m][j][q] + bv);
            }
        } else {
            int n = bx >> 1, sBase = ((bx & 1) << 7) + rloc;
#pragma unroll
            for (int j = 0; j < 4; ++j) {
                int jl = (j0 - 1024) + wc + (j << 4) + (lane & 15);  // 0..511
                float bv = bqkv[1024 + jl];
                f16x4 vv;
#pragma unroll
                for (int q = 0; q < 4; ++q) vv[q] = (f16)(acc[m][j][q] + bv);
                *(f16x4*)(vT + ((n * H_ + (jl >> 6)) * 64 + (jl & 63)) * S_ + sBase) = vv;
            }
        }
    }
}

// partial logits: logP[sk][h][s][t] = sum_{n in chunk, d} q[n,s,h,d]*k[n,t,h,d]
// 48 steps of (ni, d-half), BK=32 double-buffered prefetch, syncthreads-fenced.
__global__ __launch_bounds__(256) void k_logits(const f16* __restrict__ qk,
                                                float* __restrict__ logP) {
    int wg = (blockIdx.x & 7) * 64 + (blockIdx.x >> 3);     // 512 = 8*64 exact
    int sk = wg >> 5, rem = wg & 31, h = rem >> 2, sb = (rem >> 1) & 1, tb = rem & 1;
    int s0 = sb << 7, t0 = tb << 7, n0 = sk * NPK;
    int tid = threadIdx.x, lane = tid & 63, wid = tid >> 6;
    int wr = (wid >> 1) << 6, wc = (wid & 1) << 6;
    __shared__ f16 As[2][128 * 32];
    __shared__ f16 Bs[2][128 * 32];
    const f16* Aroot = qk + s0 * 1024 + (h << 6);
    const f16* Broot = qk + t0 * 1024 + 512 + (h << 6);
    f32x4 acc[4][4] = {};
    stage_tile(Aroot + n0 * S_ * 1024, Broot + n0 * S_ * 1024, 1024,
               As[0], Bs[0], tid, wid);
    __syncthreads();
    for (int t = 0; t < 2 * NPK; ++t) {
        int cur = t & 1;
        if (t < 2 * NPK - 1) {
            int tn = t + 1;
            int n = n0 + (tn >> 1), dh = (tn & 1) << 5;
            stage_tile(Aroot + n * S_ * 1024 + dh, Broot + n * S_ * 1024 + dh, 1024,
                       As[cur ^ 1], Bs[cur ^ 1], tid, wid);
        }
        frag_mma(As[cur], Bs[cur], lane, wr, wc, acc);
        __syncthreads();
    }
#pragma unroll
    for (int m = 0; m < 4; ++m) {
        int rloc = wr + (m << 4) + ((lane >> 4) << 2);
#pragma unroll
        for (int j = 0; j < 4; ++j) {
            int tc = t0 + wc + (j << 4) + (lane & 15);
#pragma unroll
            for (int q = 0; q < 4; ++q)
                logP[((sk * H_ + h) * S_ + s0 + rloc + q) * S_ + tc] = acc[m][j][q];
        }
    }
}

__global__ __launch_bounds__(256) void k_softmax(const float* __restrict__ logP,
                                                 const int* __restrict__ mask,
                                                 f16* __restrict__ attn) {
    int hs = blockIdx.x;  // h*256 + s
    int t = threadIdx.x, lane = t & 63, wid = t >> 6;
    float v = 0.f;
#pragma unroll
    for (int sk = 0; sk < SPLITK; ++sk)
        v += logP[(sk * H_ * S_ + hs) * S_ + t];
    v *= 0.125f;
    if (mask[t] == 0) v = -1e9f;
    __shared__ float redm[4], reds[4];
    float m_ = v;
    for (int o = 32; o > 0; o >>= 1) m_ = fmaxf(m_, __shfl_xor(m_, o));
    if (lane == 0) redm[wid] = m_;
    __syncthreads();
    float bm = fmaxf(fmaxf(redm[0], redm[1]), fmaxf(redm[2], redm[3]));
    float e = __expf(v - bm);
    float s_ = e;
    for (int o = 32; o > 0; o >>= 1) s_ += __shfl_xor(s_, o);
    if (lane == 0) reds[wid] = s_;
    __syncthreads();
    float tot = reds[0] + reds[1] + reds[2] + reds[3];
    attn[hs * S_ + t] = (f16)(e / tot);
}

// attn_out[n][s][h*64+d] = sum_t attn[h][s][t] * vT[n][h][d][t]
__global__ __launch_bounds__(256) void k_pv(const f16* __restrict__ attn,
                                            const f16* __restrict__ vT,
                                            f16* __restrict__ attn_out) {
    int n = blockIdx.x >> 3, h = blockIdx.x & 7;
    int tid = threadIdx.x, lane = tid & 63, wid = tid >> 6;
    __shared__ f16 As[256 * 32];
    __shared__ f16 Bs[64 * 32];
    f32x4 acc[4][4] = {};
    for (int tt = 0; tt < 8; ++tt) {
        int t0 = tt << 5;
        __syncthreads();
#pragma unroll
        for (int i = 0; i < 4; ++i) {
            int id = tid + (i << 8);
            int sr = id >> 2, c4 = id & 3;
            *(f16x8*)&As[sr * 32 + (c4 << 3)] =
                *(const f16x8*)(attn + (h * S_ + sr) * S_ + t0 + (c4 << 3));
        }
        {
            int d = tid >> 2, c4 = tid & 3;
            *(f16x8*)&Bs[d * 32 + (c4 << 3)] =
                *(const f16x8*)(vT + ((n * H_ + h) * 64 + d) * S_ + t0 + (c4 << 3));
        }
        __syncthreads();
        f16x8 af[4], bf[4];
#pragma unroll
        for (int m = 0; m < 4; ++m)
            af[m] = *(const f16x8*)&As[(wid * 64 + m * 16 + (lane & 15)) * 32 + ((lane >> 4) << 3)];
#pragma unroll
        for (int j = 0; j < 4; ++j)
            bf[j] = *(const f16x8*)&Bs[(j * 16 + (lane & 15)) * 32 + ((lane >> 4) << 3)];
#pragma unroll
        for (int m = 0; m < 4; ++m)
#pragma unroll
            for (int j = 0; j < 4; ++j)
                acc[m][j] = MFMA16(af[m], bf[j], acc[m][j]);
    }
#pragma unroll
    for (int m = 0; m < 4; ++m) {
        int sl = wid * 64 + m * 16 + ((lane >> 4) << 2);
#pragma unroll
        for (int j = 0; j < 4; ++j) {
            int d = j * 16 + (lane & 15);
#pragma unroll
            for (int q = 0; q < 4; ++q)
                attn_out[(n * S_ + sl + q) * C_ + h * 64 + d] = (f16)acc[m][j][q];
        }
    }
}

// y = attn_out @ Wout^T + bout; x = msaT + y; LayerNorm(x) -> out[s][n][c]
__global__ __launch_bounds__(512) void k_out_ln(const f16* __restrict__ attn_out,
                                                const f16* __restrict__ Wo,
                                                const float* __restrict__ bout,
                                                const f16* __restrict__ msaT,
                                                const float* __restrict__ gamma,
                                                const float* __restrict__ beta,
                                                float* __restrict__ out) {
    int r0 = blockIdx.x << 6;
    int n = r0 >> 8, s0 = r0 & 255;
    int tid = threadIdx.x, lane = tid & 63, wid = tid >> 6;
    __shared__ f16 As[64 * 32];
    __shared__ f16 Bs[512 * 32];
    __shared__ float redS[8][64], redQ[8][64], muS[64], rsS[64];
    f32x4 acc[4][4] = {};
    for (int kt = 0; kt < 16; ++kt) {
        int c0 = kt << 5;
        __syncthreads();
        if (tid < 256) {
            int row = tid >> 2, c4 = tid & 3;
            *(f16x8*)&As[row * 32 + (c4 << 3)] =
                *(const f16x8*)(attn_out + (r0 + row) * C_ + c0 + (c4 << 3));
        }
#pragma unroll
        for (int i = 0; i < 4; ++i) {
            int id = tid + (i << 9);
            int row = id >> 2, c4 = id & 3;
            *(f16x8*)&Bs[row * 32 + (c4 << 3)] =
                *(const f16x8*)(Wo + row * C_ + c0 + (c4 << 3));
        }
        __syncthreads();
        f16x8 af[4], bf[4];
#pragma unroll
        for (int m = 0; m < 4; ++m)
            af[m] = *(const f16x8*)&As[((m << 4) + (lane & 15)) * 32 + ((lane >> 4) << 3)];
#pragma unroll
        for (int j = 0; j < 4; ++j)
            bf[j] = *(const f16x8*)&Bs[((wid << 6) + (j << 4) + (lane & 15)) * 32 + ((lane >> 4) << 3)];
#pragma unroll
        for (int m = 0; m < 4; ++m)
#pragma unroll
            for (int j = 0; j < 4; ++j)
                acc[m][j] = MFMA16(af[m], bf[j], acc[m][j]);
    }
    float psum[4][4] = {}, psq[4][4] = {};
#pragma unroll
    for (int m = 0; m < 4; ++m)
#pragma unroll
        for (int j = 0; j < 4; ++j) {
            int c = (wid << 6) + (j << 4) + (lane & 15);
            float bj = bout[c];
#pragma unroll
            for (int q = 0; q < 4; ++q) {
                int rl = (m << 4) + ((lane >> 4) << 2) + q;
                float x = acc[m][j][q] + bj + (float)msaT[(r0 + rl) * C_ + c];
                acc[m][j][q] = x;
                psum[m][q] += x;
                psq[m][q] += x * x;
            }
        }
#pragma unroll
    for (int m = 0; m < 4; ++m)
#pragma unroll
        for (int q = 0; q < 4; ++q)
            for (int o = 1; o < 16; o <<= 1) {
                psum[m][q] += __shfl_xor(psum[m][q], o);
                psq[m][q]  += __shfl_xor(psq[m][q], o);
            }
    if ((lane & 15) == 0) {
#pragma unroll
        for (int m = 0; m < 4; ++m)
#pragma unroll
            for (int q = 0; q < 4; ++q) {
                int rl = (m << 4) + ((lane >> 4) << 2) + q;
                redS[wid][rl] = psum[m][q];
                redQ[wid][rl] = psq[m][q];
            }
    }
    __syncthreads();
    if (tid < 64) {
        float t1 = 0.f, t2 = 0.f;
#pragma unroll
        for (int w = 0; w < 8; ++w) { t1 += redS[w][tid]; t2 += redQ[w][tid]; }
        float mu = t1 * (1.0f / 512.0f);
        float var = t2 * (1.0f / 512.0f) - mu * mu;
        muS[tid] = mu;
        rsS[tid] = rsqrtf(var + 1e-5f);
    }
    __syncthreads();
#pragma unroll
    for (int m = 0; m < 4; ++m)
#pragma unroll
        for (int j = 0; j < 4; ++j) {
            int c = (wid << 6) + (j << 4) + (lane & 15);
            float g = gamma[c], bb = beta[c];
#pragma unroll
            for (int q = 0; q < 4; ++q) {
                int rl = (m << 4) + ((lane >> 4) << 2) + q;
                int s = s0 + rl;
                float y = (acc[m][j][q] - muS[rl]) * rsS[rl] * g + bb;
                out[(s * N_ + n) * C_ + c] = y;
            }
        }
}

extern "C" void kernel_launch(void* const* d_in, const int* in_sizes, int n_in,
                              void* d_out, int out_size, void* d_ws, size_t ws_size,
                              hipStream_t stream) {
    const float* msa   = (const float*)d_in[0];
    const int*   mask  = (const int*)d_in[1];
    const float* Wqkv  = (const float*)d_in[2];
    const float* bqkv  = (const float*)d_in[3];
    const float* Wout  = (const float*)d_in[4];
    const float* bout  = (const float*)d_in[5];
    const float* gamma = (const float*)d_in[6];
    const float* beta  = (const float*)d_in[7];
    float* out = (float*)d_out;
    char* ws = (char*)d_ws;

    f16*   qk   = (f16*)(ws);                        // 201,326,592 B
    f16*   vT   = (f16*)(ws + 201326592);            // 100,663,296 B
    f16*   msaT = (f16*)(ws + 301989888);            // 100,663,296 B
    float* logP = (float*)(ws + 402653184);          //  33,554,432 B
    f16*   attn = (f16*)(ws + 436207616);            //   1,048,576 B
    f16*   Wq16 = (f16*)(ws + 437256192);            //   1,572,864 B
    f16*   Wo16 = (f16*)(ws + 438829056);            //     524,288 B
    f16*   attn_out = qk;                            // alias: q/k dead after k_logits

    k_prep<<<dim3(3072), dim3(256), 0, stream>>>(Wqkv, Wout, Wq16, Wo16);
    k_cast<<<dim3(24576), dim3(256), 0, stream>>>(msa, msaT);
    k_qkv<<<dim3(9216), dim3(256), 0, stream>>>(msaT, Wq16, bqkv, qk, vT);
    k_logits<<<dim3(512), dim3(256), 0, stream>>>(qk, logP);
    k_softmax<<<dim3(2048), dim3(256), 0, stream>>>(logP, mask, attn);
    k_pv<<<dim3(3072), dim3(256), 0, stream>>>(attn, vT, attn_out);
    k_out_ln<<<dim3(1536), dim3(512), 0, stream>>>(attn_out, Wo16, bout, msaT, gamma, beta, out);
}

// Round 5
// 628.506 us; speedup vs baseline: 1.1224x; 1.0115x over previous
//
#include <hip/hip_runtime.h>

#define S_ 256
#define N_ 384
#define C_ 512
#define H_ 8
#define R_ (N_*S_)
#define SPLITK 32
#define NPK (N_/SPLITK)   // 12

typedef _Float16 f16;
typedef _Float16 f16x8 __attribute__((ext_vector_type(8)));
typedef float f32x4 __attribute__((ext_vector_type(4)));

#define MFMA16(a,b,c) __builtin_amdgcn_mfma_f32_16x16x32_f16(a,b,c,0,0,0)

typedef __attribute__((address_space(3))) unsigned int as3_u32;
typedef __attribute__((address_space(1))) const unsigned int as1_u32;

// async global->LDS, 16B per lane; l must be the wave-uniform base
__device__ __forceinline__ void gl_lds16(const void* g, void* l) {
    __builtin_amdgcn_global_load_lds((as1_u32*)(unsigned long long)g,
                                     (as3_u32*)(unsigned long long)l, 16, 0, 0);
}

// [row][64] f16 tile; granule (8 f16 = 16B) XOR-swizzled with row&7
__device__ __forceinline__ int swz_off(int row, int g) {
    return row*64 + (((g) ^ (row & 7)) << 3);
}

// ---- [row][32] tile helpers (k_qkv, k_logits; unchanged from R4) ----
__device__ __forceinline__ void stage_tile32(const f16* __restrict__ Ab,
                                             const f16* __restrict__ Bb,
                                             int stride, f16* As_, f16* Bs_,
                                             int tid, int wid) {
#pragma unroll
    for (int i = 0; i < 2; ++i) {
        int id = (i << 8) + tid;
        int row = id >> 2;
        int g = (id & 3) ^ ((row >> 1) & 3);
        int lofs = ((i << 8) + (wid << 6)) << 4;   // wave-uniform LDS byte base
        gl_lds16(Ab + row * stride + (g << 3), (char*)As_ + lofs);
        gl_lds16(Bb + row * stride + (g << 3), (char*)Bs_ + lofs);
    }
}

__device__ __forceinline__ void frag_mma32(const f16* As_, const f16* Bs_,
                                           int lane, int wr, int wc, f32x4 acc[4][4]) {
    int kg = lane >> 4;
    f16x8 af[4], bf[4];
#pragma unroll
    for (int m = 0; m < 4; ++m) {
        int row = wr + (m << 4) + (lane & 15);
        af[m] = *(const f16x8*)&As_[row * 32 + ((kg ^ ((row >> 1) & 3)) << 3)];
    }
#pragma unroll
    for (int j = 0; j < 4; ++j) {
        int row = wc + (j << 4) + (lane & 15);
        bf[j] = *(const f16x8*)&Bs_[row * 32 + ((kg ^ ((row >> 1) & 3)) << 3)];
    }
#pragma unroll
    for (int m = 0; m < 4; ++m)
#pragma unroll
        for (int j = 0; j < 4; ++j)
            acc[m][j] = MFMA16(af[m], bf[j], acc[m][j]);
}

// ---- K=64 MFMA step from [row][64] swizzled LDS tiles ----
__device__ __forceinline__ void frag_mma64(const f16* As_, const f16* Bs_,
                                           int lane, int wr, int wc, f32x4 acc[4][4]) {
#pragma unroll
    for (int ks = 0; ks < 64; ks += 32) {
        int kg = (ks >> 3) + (lane >> 4);
        f16x8 af[4], bf[4];
#pragma unroll
        for (int m = 0; m < 4; ++m)
            af[m] = *(const f16x8*)&As_[swz_off(wr + (m << 4) + (lane & 15), kg)];
#pragma unroll
        for (int j = 0; j < 4; ++j)
            bf[j] = *(const f16x8*)&Bs_[swz_off(wc + (j << 4) + (lane & 15), kg)];
#pragma unroll
        for (int m = 0; m < 4; ++m)
#pragma unroll
            for (int j = 0; j < 4; ++j)
                acc[m][j] = MFMA16(af[m], bf[j], acc[m][j]);
    }
}

__global__ __launch_bounds__(256) void k_prep(const float* __restrict__ Wqkv,
                                              const float* __restrict__ Wout,
                                              f16* __restrict__ Wq16, f16* __restrict__ Wo16) {
    int i = blockIdx.x * 256 + threadIdx.x;
    if (i < 1536 * C_) Wq16[i] = (f16)Wqkv[i];
    if (i < C_ * C_)   Wo16[i] = (f16)Wout[i];
}

// msaT[r=(n*256+s)][c] = (f16)msa[s][n][c]
__global__ __launch_bounds__(256) void k_cast(const float* __restrict__ msa,
                                              f16* __restrict__ msaT) {
    int t = blockIdx.x * 256 + threadIdx.x;
    int r = t >> 6, cg = t & 63;
    int n = r >> 8, s = r & 255;
    const float* src = msa + (s * N_ + n) * C_ + (cg << 3);
    float4 lo = *(const float4*)src;
    float4 hi = *(const float4*)(src + 4);
    f16x8 v;
    v[0]=(f16)lo.x; v[1]=(f16)lo.y; v[2]=(f16)lo.z; v[3]=(f16)lo.w;
    v[4]=(f16)hi.x; v[5]=(f16)hi.y; v[6]=(f16)hi.z; v[7]=(f16)hi.w;
    *(f16x8*)(msaT + r * C_ + (cg << 3)) = v;
}

// qk[r][j](j<1024: q|k) and vT[n][h][d][t] from msaT @ Wqkv^T + bqkv
__global__ __launch_bounds__(256) void k_qkv(const f16* __restrict__ msaT,
                                             const f16* __restrict__ W,
                                             const float* __restrict__ bqkv,
                                             f16* __restrict__ qk,
                                             f16* __restrict__ vT) {
    int wg = (blockIdx.x & 7) * 1152 + (blockIdx.x >> 3);   // 9216 = 8*1152 exact
    int bx = wg / 12, by = wg % 12;
    int j0 = by << 7;
    int tid = threadIdx.x, lane = tid & 63, wid = tid >> 6;
    int wr = (wid >> 1) << 6, wc = (wid & 1) << 6;
    __shared__ f16 SH[16384];                    // 2x(As 4096) + 2x(Bs 4096)
    const f16* Abase = msaT + (bx << 7) * C_;
    const f16* Bbase = W + j0 * C_;
    f32x4 acc[4][4] = {};
    stage_tile32(Abase, Bbase, C_, SH, SH + 8192, tid, wid);
    __syncthreads();
    for (int t = 0; t < 16; ++t) {
        int cur = t & 1;
        if (t < 15)
            stage_tile32(Abase + ((t + 1) << 5), Bbase + ((t + 1) << 5), C_,
                         SH + ((cur ^ 1) << 12), SH + 8192 + ((cur ^ 1) << 12), tid, wid);
        frag_mma32(SH + (cur << 12), SH + 8192 + (cur << 12), lane, wr, wc, acc);
        __syncthreads();
    }
    // ---- epilogue: LDS-staged coalesced stores ----
    if (by < 8) {
        // q/k path: rows out; two passes of 64 rows staged as [64][136]
#pragma unroll
        for (int p = 0; p < 2; ++p) {
            __syncthreads();
#pragma unroll
            for (int mm = 0; mm < 2; ++mm) {
                int m = 2 * p + mm;
                int rl = (m << 4) + ((lane >> 4) << 2);       // rloc - wr
                int lrow = (wr >> 1) + rl - (p << 5);          // 0..63
#pragma unroll
                for (int j = 0; j < 4; ++j) {
                    int col = wc + (j << 4) + (lane & 15);
                    float bv = bqkv[j0 + col];
#pragma unroll
                    for (int q = 0; q < 4; ++q)
                        SH[(lrow + q) * 136 + col] = (f16)(acc[m][j][q] + bv);
                }
            }
            __syncthreads();
#pragma unroll
            for (int i = 0; i < 4; ++i) {
                int u = tid + (i << 8);
                int lrow = u >> 4, seg = u & 15;
                int grow = (bx << 7) + ((lrow >> 5) << 6) + (p << 5) + (lrow & 31);
                *(f16x8*)(qk + grow * 1024 + j0 + (seg << 3)) =
                    *(const f16x8*)&SH[lrow * 136 + (seg << 3)];
            }
        }
    } else {
        // v path: transposed out, staged as [64 cols][128 rows] -> vT rows
        int n = bx >> 1, t0g = (bx & 1) << 7;
#pragma unroll
        for (int p = 0; p < 2; ++p) {
            __syncthreads();
#pragma unroll
            for (int m = 0; m < 4; ++m) {
                int rl = wr + (m << 4) + ((lane >> 4) << 2);   // 0..127
#pragma unroll
                for (int jj = 0; jj < 2; ++jj) {
                    int j = 2 * p + jj;
                    int col = wc + (j << 4) + (lane & 15);
                    int lcol = (col & 31) + ((col >> 6) << 5); // 0..63
                    float bv = bqkv[1024 + (by - 8) * 128 + col];
#pragma unroll
                    for (int q = 0; q < 4; ++q)
                        SH[lcol * 136 + rl + q] = (f16)(acc[m][j][q] + bv);
                }
            }
            __syncthreads();
#pragma unroll
            for (int i = 0; i < 4; ++i) {
                int u = tid + (i << 8);
                int lcol = u >> 4, seg = u & 15;
                int col = (lcol & 31) + (p << 5) + ((lcol >> 5) << 6);
                int jg = (by - 8) * 128 + col;
                *(f16x8*)(vT + ((n * H_ + (jg >> 6)) * 64 + (jg & 63)) * S_ + t0g + (seg << 3)) =
                    *(const f16x8*)&SH[lcol * 136 + (seg << 3)];
            }
        }
    }
}

// partial logits: logP[sk][h][s][t] = sum_{n in chunk, d} q[n,s,h,d]*k[n,t,h,d]
__global__ __launch_bounds__(256) void k_logits(const f16* __restrict__ qk,
                                                float* __restrict__ logP) {
    int wg = (blockIdx.x & 7) * 128 + (blockIdx.x >> 3);    // 1024 = 8*128 exact
    int sk = wg >> 5, rem = wg & 31, h = rem >> 2, sb = (rem >> 1) & 1, tb = rem & 1;
    int s0 = sb << 7, t0 = tb << 7, n0 = sk * NPK;
    int tid = threadIdx.x, lane = tid & 63, wid = tid >> 6;
    int wr = (wid >> 1) << 6, wc = (wid & 1) << 6;
    __shared__ f16 SH[16384];
    const f16* Aroot = qk + s0 * 1024 + (h << 6);
    const f16* Broot = qk + t0 * 1024 + 512 + (h << 6);
    f32x4 acc[4][4] = {};
    stage_tile32(Aroot + n0 * S_ * 1024, Broot + n0 * S_ * 1024, 1024,
                 SH, SH + 8192, tid, wid);
    __syncthreads();
    for (int t = 0; t < 2 * NPK; ++t) {
        int cur = t & 1;
        if (t < 2 * NPK - 1) {
            int tn = t + 1;
            int n = n0 + (tn >> 1), dh = (tn & 1) << 5;
            stage_tile32(Aroot + n * S_ * 1024 + dh, Broot + n * S_ * 1024 + dh, 1024,
                         SH + ((cur ^ 1) << 12), SH + 8192 + ((cur ^ 1) << 12), tid, wid);
        }
        frag_mma32(SH + (cur << 12), SH + 8192 + (cur << 12), lane, wr, wc, acc);
        __syncthreads();
    }
#pragma unroll
    for (int m = 0; m < 4; ++m) {
        int rloc = wr + (m << 4) + ((lane >> 4) << 2);
#pragma unroll
        for (int j = 0; j < 4; ++j) {
            int tc = t0 + wc + (j << 4) + (lane & 15);
#pragma unroll
            for (int q = 0; q < 4; ++q)
                logP[((sk * H_ + h) * S_ + s0 + rloc + q) * S_ + tc] = acc[m][j][q];
        }
    }
}

__global__ __launch_bounds__(256) void k_softmax(const float* __restrict__ logP,
                                                 const int* __restrict__ mask,
                                                 f16* __restrict__ attn) {
    int hs = blockIdx.x;  // h*256 + s
    int t = threadIdx.x, lane = t & 63, wid = t >> 6;
    float v = 0.f;
#pragma unroll
    for (int sk = 0; sk < SPLITK; ++sk)
        v += logP[(sk * H_ * S_ + hs) * S_ + t];
    v *= 0.125f;
    if (mask[t] == 0) v = -1e9f;
    __shared__ float redm[4], reds[4];
    float m_ = v;
    for (int o = 32; o > 0; o >>= 1) m_ = fmaxf(m_, __shfl_xor(m_, o));
    if (lane == 0) redm[wid] = m_;
    __syncthreads();
    float bm = fmaxf(fmaxf(redm[0], redm[1]), fmaxf(redm[2], redm[3]));
    float e = __expf(v - bm);
    float s_ = e;
    for (int o = 32; o > 0; o >>= 1) s_ += __shfl_xor(s_, o);
    if (lane == 0) reds[wid] = s_;
    __syncthreads();
    float tot = reds[0] + reds[1] + reds[2] + reds[3];
    attn[hs * S_ + t] = (f16)(e / tot);
}

// attn_out[n][s][h*64+d] = sum_t attn[h][s][t] * vT[n][h][d][t]
// BK=64, gl_lds staging, swizzled [row][64] tiles, LDS-coalesced epilogue.
__global__ __launch_bounds__(256) void k_pv(const f16* __restrict__ attn,
                                            const f16* __restrict__ vT,
                                            f16* __restrict__ attn_out) {
    int n = blockIdx.x >> 3, h = blockIdx.x & 7;
    int tid = threadIdx.x, lane = tid & 63, wid = tid >> 6;
    __shared__ f16 SH[20480];                    // As 256x64 (16384) + Bs 64x64 (4096)
    f16* As_ = SH;
    f16* Bs_ = SH + 16384;
    f32x4 acc[4][4] = {};
    const f16* Ab = attn + h * S_ * S_;
    const f16* Bb = vT + (n * H_ + h) * 64 * S_;
    for (int tt = 0; tt < 4; ++tt) {
        int t0 = tt << 6;
        __syncthreads();
#pragma unroll
        for (int i = 0; i < 8; ++i) {           // As: 256 rows x 64
            int id = (i << 8) + tid;
            int row = id >> 3, g = (id & 7) ^ (row & 7);
            int lofs = ((i << 8) + (wid << 6)) << 4;
            gl_lds16(Ab + row * S_ + t0 + (g << 3), (char*)As_ + lofs);
        }
#pragma unroll
        for (int i = 0; i < 2; ++i) {           // Bs: 64 rows x 64
            int id = (i << 8) + tid;
            int row = id >> 3, g = (id & 7) ^ (row & 7);
            int lofs = ((i << 8) + (wid << 6)) << 4;
            gl_lds16(Bb + row * S_ + t0 + (g << 3), (char*)Bs_ + lofs);
        }
        __syncthreads();
        frag_mma64(As_, Bs_, lane, wid << 6, 0, acc);
    }
    // epilogue: stage [128][72] halves, coalesced f16x8 stores
#pragma unroll
    for (int p = 0; p < 2; ++p) {
        __syncthreads();
#pragma unroll
        for (int mm = 0; mm < 2; ++mm) {
            int m = 2 * p + mm;
            int rl = ((m & 1) << 4) + ((lane >> 4) << 2);   // 0..28 (+q)
            int lrow = (wid << 5) + rl;                      // 0..127
#pragma unroll
            for (int j = 0; j < 4; ++j) {
                int d = (j << 4) + (lane & 15);
#pragma unroll
                for (int q = 0; q < 4; ++q)
                    SH[(lrow + q) * 72 + d] = (f16)acc[m][j][q];
            }
        }
        __syncthreads();
#pragma unroll
        for (int i = 0; i < 4; ++i) {
            int u = tid + (i << 8);
            int row = u >> 3, seg = u & 7;
            int s = ((row >> 5) << 6) + (p << 5) + (row & 31);
            *(f16x8*)(attn_out + (n * S_ + s) * C_ + (h << 6) + (seg << 3)) =
                *(const f16x8*)&SH[row * 72 + (seg << 3)];
        }
    }
}

// y = attn_out @ Wout^T + bout; x = msaT + y; LayerNorm(x) -> out[s][n][c]
__global__ __launch_bounds__(512) void k_out_ln(const f16* __restrict__ attn_out,
                                                const f16* __restrict__ Wo,
                                                const float* __restrict__ bout,
                                                const f16* __restrict__ msaT,
                                                const float* __restrict__ gamma,
                                                const float* __restrict__ beta,
                                                float* __restrict__ out) {
    int r0 = blockIdx.x << 6;
    int n = r0 >> 8, s0 = r0 & 255;
    int tid = threadIdx.x, lane = tid & 63, wid = tid >> 6;
    __shared__ f16 SH[36864];                    // As 64x64 (4096) + Bs 512x64 (32768)
    f16* As_ = SH;
    f16* Bs_ = SH + 4096;
    __shared__ float redS[8][64], redQ[8][64], muS[64], rsS[64];
    f32x4 acc[4][4] = {};
    for (int kt = 0; kt < 8; ++kt) {
        int c0 = kt << 6;
        __syncthreads();
        {                                         // As: 64 rows x 64 (1 instr/thread)
            int row = tid >> 3, g = (tid & 7) ^ (row & 7);
            int lofs = (wid << 6) << 4;
            gl_lds16(attn_out + (r0 + row) * C_ + c0 + (g << 3), (char*)As_ + lofs);
        }
#pragma unroll
        for (int i = 0; i < 8; ++i) {             // Bs: 512 rows x 64
            int id = (i << 9) + tid;
            int row = id >> 3, g = (id & 7) ^ (row & 7);
            int lofs = ((i << 9) + (wid << 6)) << 4;
            gl_lds16(Wo + row * C_ + c0 + (g << 3), (char*)Bs_ + lofs);
        }
        __syncthreads();
        frag_mma64(As_, Bs_, lane, 0, wid << 6, acc);
    }
    float psum[4][4] = {}, psq[4][4] = {};
#pragma unroll
    for (int m = 0; m < 4; ++m)
#pragma unroll
        for (int j = 0; j < 4; ++j) {
            int c = (wid << 6) + (j << 4) + (lane & 15);
            float bj = bout[c];
#pragma unroll
            for (int q = 0; q < 4; ++q) {
                int rl = (m << 4) + ((lane >> 4) << 2) + q;
                float x = acc[m][j][q] + bj + (float)msaT[(r0 + rl) * C_ + c];
                acc[m][j][q] = x;
                psum[m][q] += x;
                psq[m][q] += x * x;
            }
        }
#pragma unroll
    for (int m = 0; m < 4; ++m)
#pragma unroll
        for (int q = 0; q < 4; ++q)
            for (int o = 1; o < 16; o <<= 1) {
                psum[m][q] += __shfl_xor(psum[m][q], o);
                psq[m][q]  += __shfl_xor(psq[m][q], o);
            }
    if ((lane & 15) == 0) {
#pragma unroll
        for (int m = 0; m < 4; ++m)
#pragma unroll
            for (int q = 0; q < 4; ++q) {
                int rl = (m << 4) + ((lane >> 4) << 2) + q;
                redS[wid][rl] = psum[m][q];
                redQ[wid][rl] = psq[m][q];
            }
    }
    __syncthreads();
    if (tid < 64) {
        float t1 = 0.f, t2 = 0.f;
#pragma unroll
        for (int w = 0; w < 8; ++w) { t1 += redS[w][tid]; t2 += redQ[w][tid]; }
        float mu = t1 * (1.0f / 512.0f);
        float var = t2 * (1.0f / 512.0f) - mu * mu;
        muS[tid] = mu;
        rsS[tid] = rsqrtf(var + 1e-5f);
    }
    __syncthreads();
#pragma unroll
    for (int m = 0; m < 4; ++m)
#pragma unroll
        for (int j = 0; j < 4; ++j) {
            int c = (wid << 6) + (j << 4) + (lane & 15);
            float g = gamma[c], bb = beta[c];
#pragma unroll
            for (int q = 0; q < 4; ++q) {
                int rl = (m << 4) + ((lane >> 4) << 2) + q;
                int s = s0 + rl;
                float y = (acc[m][j][q] - muS[rl]) * rsS[rl] * g + bb;
                out[(s * N_ + n) * C_ + c] = y;
            }
        }
}

extern "C" void kernel_launch(void* const* d_in, const int* in_sizes, int n_in,
                              void* d_out, int out_size, void* d_ws, size_t ws_size,
                              hipStream_t stream) {
    const float* msa   = (const float*)d_in[0];
    const int*   mask  = (const int*)d_in[1];
    const float* Wqkv  = (const float*)d_in[2];
    const float* bqkv  = (const float*)d_in[3];
    const float* Wout  = (const float*)d_in[4];
    const float* bout  = (const float*)d_in[5];
    const float* gamma = (const float*)d_in[6];
    const float* beta  = (const float*)d_in[7];
    float* out = (float*)d_out;
    char* ws = (char*)d_ws;

    f16*   qk   = (f16*)(ws);                        // 201,326,592 B
    f16*   vT   = (f16*)(ws + 201326592);            // 100,663,296 B
    f16*   msaT = (f16*)(ws + 301989888);            // 100,663,296 B
    f16*   attn = (f16*)(ws + 402653184);            //   1,048,576 B
    f16*   Wq16 = (f16*)(ws + 403701760);            //   1,572,864 B
    f16*   Wo16 = (f16*)(ws + 405274624);            //     524,288 B
    float* logP = out;                               // d_out as scratch (67 MB of 201 MB);
                                                     // k_out_ln overwrites d_out last
    f16*   attn_out = qk;                            // alias: q/k dead after k_logits

    k_prep<<<dim3(3072), dim3(256), 0, stream>>>(Wqkv, Wout, Wq16, Wo16);
    k_cast<<<dim3(24576), dim3(256), 0, stream>>>(msa, msaT);
    k_qkv<<<dim3(9216), dim3(256), 0, stream>>>(msaT, Wq16, bqkv, qk, vT);
    k_logits<<<dim3(1024), dim3(256), 0, stream>>>(qk, logP);
    k_softmax<<<dim3(2048), dim3(256), 0, stream>>>(logP, mask, attn);
    k_pv<<<dim3(3072), dim3(256), 0, stream>>>(attn, vT, attn_out);
    k_out_ln<<<dim3(1536), dim3(512), 0, stream>>>(attn_out, Wo16, bout, msaT, gamma, beta, out);
}

// Round 6
// 580.224 us; speedup vs baseline: 1.2158x; 1.0832x over previous
//
#include <hip/hip_runtime.h>

#define S_ 256
#define N_ 384
#define C_ 512
#define H_ 8
#define R_ (N_*S_)
#define SPLITK 32
#define NPK (N_/SPLITK)   // 12

typedef _Float16 f16;
typedef _Float16 f16x8 __attribute__((ext_vector_type(8)));
typedef float f32x4 __attribute__((ext_vector_type(4)));

#define MFMA16(a,b,c) __builtin_amdgcn_mfma_f32_16x16x32_f16(a,b,c,0,0,0)

typedef __attribute__((address_space(3))) unsigned int as3_u32;
typedef __attribute__((address_space(1))) const unsigned int as1_u32;

// async global->LDS, 16B per lane; l must be the wave-uniform base
__device__ __forceinline__ void gl_lds16(const void* g, void* l) {
    __builtin_amdgcn_global_load_lds((as1_u32*)(unsigned long long)g,
                                     (as3_u32*)(unsigned long long)l, 16, 0, 0);
}

// [row][64] f16 tile; granule (8 f16 = 16B) XOR-swizzled with row&7
__device__ __forceinline__ int swz_off(int row, int g) {
    return row*64 + (((g) ^ (row & 7)) << 3);
}

// ---- 512-thread staging of a [128][64] f16 tile pair; linear LDS dest,
// inverse-swizzled global source (rule #21). 4 gl_lds per thread. ----
__device__ __forceinline__ void stage8(const f16* __restrict__ Ab,
                                       const f16* __restrict__ Bb,
                                       int stride, f16* As_, f16* Bs_,
                                       int tid, int wid) {
#pragma unroll
    for (int i = 0; i < 2; ++i) {
        int id = (i << 9) + tid;
        int row = id >> 3, g = (id & 7) ^ (row & 7);
        int lofs = ((i << 9) + (wid << 6)) << 4;   // wave-uniform LDS byte base
        gl_lds16(Ab + row * stride + (g << 3), (char*)As_ + lofs);
        gl_lds16(Bb + row * stride + (g << 3), (char*)Bs_ + lofs);
    }
}

// ---- K=64 MFMA step, 8-wave split: wave owns 64x32 (acc[4][2]) ----
__device__ __forceinline__ void mma8(const f16* As_, const f16* Bs_,
                                     int lane, int wr, int wc, f32x4 acc[4][2]) {
#pragma unroll
    for (int ks = 0; ks < 64; ks += 32) {
        int kg = (ks >> 3) + (lane >> 4);
        f16x8 af[4], bf[2];
#pragma unroll
        for (int m = 0; m < 4; ++m)
            af[m] = *(const f16x8*)&As_[swz_off(wr + (m << 4) + (lane & 15), kg)];
#pragma unroll
        for (int j = 0; j < 2; ++j)
            bf[j] = *(const f16x8*)&Bs_[swz_off(wc + (j << 4) + (lane & 15), kg)];
#pragma unroll
        for (int m = 0; m < 4; ++m)
#pragma unroll
            for (int j = 0; j < 2; ++j)
                acc[m][j] = MFMA16(af[m], bf[j], acc[m][j]);
    }
}

// ---- K=64 MFMA step, 4-wave split (k_pv, k_out_ln): acc[4][4] ----
__device__ __forceinline__ void frag_mma64(const f16* As_, const f16* Bs_,
                                           int lane, int wr, int wc, f32x4 acc[4][4]) {
#pragma unroll
    for (int ks = 0; ks < 64; ks += 32) {
        int kg = (ks >> 3) + (lane >> 4);
        f16x8 af[4], bf[4];
#pragma unroll
        for (int m = 0; m < 4; ++m)
            af[m] = *(const f16x8*)&As_[swz_off(wr + (m << 4) + (lane & 15), kg)];
#pragma unroll
        for (int j = 0; j < 4; ++j)
            bf[j] = *(const f16x8*)&Bs_[swz_off(wc + (j << 4) + (lane & 15), kg)];
#pragma unroll
        for (int m = 0; m < 4; ++m)
#pragma unroll
            for (int j = 0; j < 4; ++j)
                acc[m][j] = MFMA16(af[m], bf[j], acc[m][j]);
    }
}

__global__ __launch_bounds__(256) void k_prep(const float* __restrict__ Wqkv,
                                              const float* __restrict__ Wout,
                                              f16* __restrict__ Wq16, f16* __restrict__ Wo16) {
    int i = blockIdx.x * 256 + threadIdx.x;
    if (i < 1536 * C_) Wq16[i] = (f16)Wqkv[i];
    if (i < C_ * C_)   Wo16[i] = (f16)Wout[i];
}

// msaT[r=(n*256+s)][c] = (f16)msa[s][n][c]
__global__ __launch_bounds__(256) void k_cast(const float* __restrict__ msa,
                                              f16* __restrict__ msaT) {
    int t = blockIdx.x * 256 + threadIdx.x;
    int r = t >> 6, cg = t & 63;
    int n = r >> 8, s = r & 255;
    const float* src = msa + (s * N_ + n) * C_ + (cg << 3);
    float4 lo = *(const float4*)src;
    float4 hi = *(const float4*)(src + 4);
    f16x8 v;
    v[0]=(f16)lo.x; v[1]=(f16)lo.y; v[2]=(f16)lo.z; v[3]=(f16)lo.w;
    v[4]=(f16)hi.x; v[5]=(f16)hi.y; v[6]=(f16)hi.z; v[7]=(f16)hi.w;
    *(f16x8*)(msaT + r * C_ + (cg << 3)) = v;
}

// qk[r][j](j<1024: q|k) and vT[n][h][d][t] from msaT @ Wqkv^T + bqkv
// 8 waves, BK=64, double-buffered, proven sync discipline.
__global__ __launch_bounds__(512) void k_qkv(const f16* __restrict__ msaT,
                                             const f16* __restrict__ W,
                                             const float* __restrict__ bqkv,
                                             f16* __restrict__ qk,
                                             f16* __restrict__ vT) {
    int wg = (blockIdx.x & 7) * 1152 + (blockIdx.x >> 3);   // 9216 = 8*1152 exact
    int bx = wg / 12, by = wg % 12;
    int j0 = by << 7;
    int tid = threadIdx.x, lane = tid & 63, wid = tid >> 6;
    int wr = (wid >> 2) << 6, wc = (wid & 3) << 5;
    __shared__ f16 SH[32768];   // As0@0, Bs0@8192, As1@16384, Bs1@24576 (f16 units)
    const f16* Abase = msaT + (bx << 7) * C_;
    const f16* Bbase = W + j0 * C_;
    f32x4 acc[4][2] = {};
    stage8(Abase, Bbase, C_, SH, SH + 8192, tid, wid);
    __syncthreads();
    for (int kt = 0; kt < 8; ++kt) {
        int cur = kt & 1;
        if (kt < 7)
            stage8(Abase + ((kt + 1) << 6), Bbase + ((kt + 1) << 6), C_,
                   SH + ((cur ^ 1) << 14), SH + 8192 + ((cur ^ 1) << 14), tid, wid);
        mma8(SH + (cur << 14), SH + 8192 + (cur << 14), lane, wr, wc, acc);
        __syncthreads();
    }
    // ---- epilogue: [128][140] stage (conflict-free strides), coalesced stores ----
    if (by < 8) {
#pragma unroll
        for (int m = 0; m < 4; ++m) {
            int rl = wr + (m << 4) + ((lane >> 4) << 2);
#pragma unroll
            for (int j = 0; j < 2; ++j) {
                int col = wc + (j << 4) + (lane & 15);
                float bv = bqkv[j0 + col];
#pragma unroll
                for (int q = 0; q < 4; ++q)
                    SH[(rl + q) * 140 + col] = (f16)(acc[m][j][q] + bv);
            }
        }
        __syncthreads();
#pragma unroll
        for (int i = 0; i < 4; ++i) {
            int u = (i << 9) + tid;
            int row = u >> 4, seg = u & 15;
            *(f16x8*)(qk + ((bx << 7) + row) * 1024 + j0 + (seg << 3)) =
                *(const f16x8*)&SH[row * 140 + (seg << 3)];
        }
    } else {
        int n = bx >> 1, t0g = (bx & 1) << 7;
#pragma unroll
        for (int m = 0; m < 4; ++m) {
            int rl = wr + (m << 4) + ((lane >> 4) << 2);
#pragma unroll
            for (int j = 0; j < 2; ++j) {
                int col = wc + (j << 4) + (lane & 15);
                float bv = bqkv[1024 + ((by - 8) << 7) + col];
#pragma unroll
                for (int q = 0; q < 4; ++q)
                    SH[col * 140 + rl + q] = (f16)(acc[m][j][q] + bv);   // transpose
            }
        }
        __syncthreads();
#pragma unroll
        for (int i = 0; i < 4; ++i) {
            int u = (i << 9) + tid;
            int lcol = u >> 4, seg = u & 15;
            int jg = ((by - 8) << 7) + lcol;
            *(f16x8*)(vT + ((n * H_ + (jg >> 6)) * 64 + (jg & 63)) * S_ + t0g + (seg << 3)) =
                *(const f16x8*)&SH[lcol * 140 + (seg << 3)];
        }
    }
}

// partial logits: logP[sk][h][s][t] = sum_{n in chunk, d} q[n,s,h,d]*k[n,t,h,d]
// 8 waves, full head-dim (K=64) per n-iteration, double-buffered.
__global__ __launch_bounds__(512) void k_logits(const f16* __restrict__ qk,
                                                float* __restrict__ logP) {
    int wg = (blockIdx.x & 7) * 128 + (blockIdx.x >> 3);    // 1024 = 8*128 exact
    int sk = wg >> 5, rem = wg & 31, h = rem >> 2, sb = (rem >> 1) & 1, tb = rem & 1;
    int s0 = sb << 7, t0 = tb << 7, n0 = sk * NPK;
    int tid = threadIdx.x, lane = tid & 63, wid = tid >> 6;
    int wr = (wid >> 2) << 6, wc = (wid & 3) << 5;
    __shared__ f16 SH[32768];
    const f16* Aroot = qk + s0 * 1024 + (h << 6);
    const f16* Broot = qk + t0 * 1024 + 512 + (h << 6);
    f32x4 acc[4][2] = {};
    stage8(Aroot + n0 * S_ * 1024, Broot + n0 * S_ * 1024, 1024,
           SH, SH + 8192, tid, wid);
    __syncthreads();
    for (int t = 0; t < NPK; ++t) {
        int cur = t & 1;
        if (t < NPK - 1) {
            int n = n0 + t + 1;
            stage8(Aroot + n * S_ * 1024, Broot + n * S_ * 1024, 1024,
                   SH + ((cur ^ 1) << 14), SH + 8192 + ((cur ^ 1) << 14), tid, wid);
        }
        mma8(SH + (cur << 14), SH + 8192 + (cur << 14), lane, wr, wc, acc);
        __syncthreads();
    }
#pragma unroll
    for (int m = 0; m < 4; ++m) {
        int rl = wr + (m << 4) + ((lane >> 4) << 2);
#pragma unroll
        for (int j = 0; j < 2; ++j) {
            int tc = t0 + wc + (j << 4) + (lane & 15);
#pragma unroll
            for (int q = 0; q < 4; ++q)
                logP[((sk * H_ + h) * S_ + s0 + rl + q) * S_ + tc] = acc[m][j][q];
        }
    }
}

__global__ __launch_bounds__(256) void k_softmax(const float* __restrict__ logP,
                                                 const int* __restrict__ mask,
                                                 f16* __restrict__ attn) {
    int hs = blockIdx.x;  // h*256 + s
    int t = threadIdx.x, lane = t & 63, wid = t >> 6;
    float v = 0.f;
#pragma unroll
    for (int sk = 0; sk < SPLITK; ++sk)
        v += logP[(sk * H_ * S_ + hs) * S_ + t];
    v *= 0.125f;
    if (mask[t] == 0) v = -1e9f;
    __shared__ float redm[4], reds[4];
    float m_ = v;
    for (int o = 32; o > 0; o >>= 1) m_ = fmaxf(m_, __shfl_xor(m_, o));
    if (lane == 0) redm[wid] = m_;
    __syncthreads();
    float bm = fmaxf(fmaxf(redm[0], redm[1]), fmaxf(redm[2], redm[3]));
    float e = __expf(v - bm);
    float s_ = e;
    for (int o = 32; o > 0; o >>= 1) s_ += __shfl_xor(s_, o);
    if (lane == 0) reds[wid] = s_;
    __syncthreads();
    float tot = reds[0] + reds[1] + reds[2] + reds[3];
    attn[hs * S_ + t] = (f16)(e / tot);
}

// attn_out[n][s][h*64+d] = sum_t attn[h][s][t] * vT[n][h][d][t]
__global__ __launch_bounds__(256) void k_pv(const f16* __restrict__ attn,
                                            const f16* __restrict__ vT,
                                            f16* __restrict__ attn_out) {
    int n = blockIdx.x >> 3, h = blockIdx.x & 7;
    int tid = threadIdx.x, lane = tid & 63, wid = tid >> 6;
    __shared__ f16 SH[20480];                    // As 256x64 (16384) + Bs 64x64 (4096)
    f16* As_ = SH;
    f16* Bs_ = SH + 16384;
    f32x4 acc[4][4] = {};
    const f16* Ab = attn + h * S_ * S_;
    const f16* Bb = vT + (n * H_ + h) * 64 * S_;
    for (int tt = 0; tt < 4; ++tt) {
        int t0 = tt << 6;
        __syncthreads();
#pragma unroll
        for (int i = 0; i < 8; ++i) {           // As: 256 rows x 64
            int id = (i << 8) + tid;
            int row = id >> 3, g = (id & 7) ^ (row & 7);
            int lofs = ((i << 8) + (wid << 6)) << 4;
            gl_lds16(Ab + row * S_ + t0 + (g << 3), (char*)As_ + lofs);
        }
#pragma unroll
        for (int i = 0; i < 2; ++i) {           // Bs: 64 rows x 64
            int id = (i << 8) + tid;
            int row = id >> 3, g = (id & 7) ^ (row & 7);
            int lofs = ((i << 8) + (wid << 6)) << 4;
            gl_lds16(Bb + row * S_ + t0 + (g << 3), (char*)Bs_ + lofs);
        }
        __syncthreads();
        frag_mma64(As_, Bs_, lane, wid << 6, 0, acc);
    }
    // epilogue: [128][140] stage halves, coalesced f16x8 stores
#pragma unroll
    for (int p = 0; p < 2; ++p) {
        __syncthreads();
#pragma unroll
        for (int mm = 0; mm < 2; ++mm) {
            int m = 2 * p + mm;
            int rl = ((m & 1) << 4) + ((lane >> 4) << 2);
            int lrow = (wid << 5) + rl;                      // 0..127
#pragma unroll
            for (int j = 0; j < 4; ++j) {
                int d = (j << 4) + (lane & 15);
#pragma unroll
                for (int q = 0; q < 4; ++q)
                    SH[(lrow + q) * 140 + d] = (f16)acc[m][j][q];
            }
        }
        __syncthreads();
#pragma unroll
        for (int i = 0; i < 4; ++i) {
            int u = tid + (i << 8);
            int row = u >> 3, seg = u & 7;
            int s = ((row >> 5) << 6) + (p << 5) + (row & 31);
            *(f16x8*)(attn_out + (n * S_ + s) * C_ + (h << 6) + (seg << 3)) =
                *(const f16x8*)&SH[row * 140 + (seg << 3)];
        }
    }
}

// y = attn_out @ Wout^T + bout; x = msaT + y; LayerNorm(x) -> out[s][n][c]
__global__ __launch_bounds__(512) void k_out_ln(const f16* __restrict__ attn_out,
                                                const f16* __restrict__ Wo,
                                                const float* __restrict__ bout,
                                                const f16* __restrict__ msaT,
                                                const float* __restrict__ gamma,
                                                const float* __restrict__ beta,
                                                float* __restrict__ out) {
    int r0 = blockIdx.x << 6;
    int n = r0 >> 8, s0 = r0 & 255;
    int tid = threadIdx.x, lane = tid & 63, wid = tid >> 6;
    __shared__ f16 SH[36864];                    // As 64x64 (4096) + Bs 512x64 (32768)
    f16* As_ = SH;
    f16* Bs_ = SH + 4096;
    __shared__ float redS[8][64], redQ[8][64], muS[64], rsS[64];
    f32x4 acc[4][4] = {};
    for (int kt = 0; kt < 8; ++kt) {
        int c0 = kt << 6;
        __syncthreads();
        {                                         // As: 64 rows x 64 (1 instr/thread)
            int row = tid >> 3, g = (tid & 7) ^ (row & 7);
            int lofs = (wid << 6) << 4;
            gl_lds16(attn_out + (r0 + row) * C_ + c0 + (g << 3), (char*)As_ + lofs);
        }
#pragma unroll
        for (int i = 0; i < 8; ++i) {             // Bs: 512 rows x 64
            int id = (i << 9) + tid;
            int row = id >> 3, g = (id & 7) ^ (row & 7);
            int lofs = ((i << 9) + (wid << 6)) << 4;
            gl_lds16(Wo + row * C_ + c0 + (g << 3), (char*)Bs_ + lofs);
        }
        __syncthreads();
        frag_mma64(As_, Bs_, lane, 0, wid << 6, acc);
    }
    float psum[4][4] = {}, psq[4][4] = {};
#pragma unroll
    for (int m = 0; m < 4; ++m)
#pragma unroll
        for (int j = 0; j < 4; ++j) {
            int c = (wid << 6) + (j << 4) + (lane & 15);
            float bj = bout[c];
#pragma unroll
            for (int q = 0; q < 4; ++q) {
                int rl = (m << 4) + ((lane >> 4) << 2) + q;
                float x = acc[m][j][q] + bj + (float)msaT[(r0 + rl) * C_ + c];
                acc[m][j][q] = x;
                psum[m][q] += x;
                psq[m][q] += x * x;
            }
        }
#pragma unroll
    for (int m = 0; m < 4; ++m)
#pragma unroll
        for (int q = 0; q < 4; ++q)
            for (int o = 1; o < 16; o <<= 1) {
                psum[m][q] += __shfl_xor(psum[m][q], o);
                psq[m][q]  += __shfl_xor(psq[m][q], o);
            }
    if ((lane & 15) == 0) {
#pragma unroll
        for (int m = 0; m < 4; ++m)
#pragma unroll
            for (int q = 0; q < 4; ++q) {
                int rl = (m << 4) + ((lane >> 4) << 2) + q;
                redS[wid][rl] = psum[m][q];
                redQ[wid][rl] = psq[m][q];
            }
    }
    __syncthreads();
    if (tid < 64) {
        float t1 = 0.f, t2 = 0.f;
#pragma unroll
        for (int w = 0; w < 8; ++w) { t1 += redS[w][tid]; t2 += redQ[w][tid]; }
        float mu = t1 * (1.0f / 512.0f);
        float var = t2 * (1.0f / 512.0f) - mu * mu;
        muS[tid] = mu;
        rsS[tid] = rsqrtf(var + 1e-5f);
    }
    __syncthreads();
#pragma unroll
    for (int m = 0; m < 4; ++m)
#pragma unroll
        for (int j = 0; j < 4; ++j) {
            int c = (wid << 6) + (j << 4) + (lane & 15);
            float g = gamma[c], bb = beta[c];
#pragma unroll
            for (int q = 0; q < 4; ++q) {
                int rl = (m << 4) + ((lane >> 4) << 2) + q;
                int s = s0 + rl;
                float y = (acc[m][j][q] - muS[rl]) * rsS[rl] * g + bb;
                out[(s * N_ + n) * C_ + c] = y;
            }
        }
}

extern "C" void kernel_launch(void* const* d_in, const int* in_sizes, int n_in,
                              void* d_out, int out_size, void* d_ws, size_t ws_size,
                              hipStream_t stream) {
    const float* msa   = (const float*)d_in[0];
    const int*   mask  = (const int*)d_in[1];
    const float* Wqkv  = (const float*)d_in[2];
    const float* bqkv  = (const float*)d_in[3];
    const float* Wout  = (const float*)d_in[4];
    const float* bout  = (const float*)d_in[5];
    const float* gamma = (const float*)d_in[6];
    const float* beta  = (const float*)d_in[7];
    float* out = (float*)d_out;
    char* ws = (char*)d_ws;

    f16*   qk   = (f16*)(ws);                        // 201,326,592 B
    f16*   vT   = (f16*)(ws + 201326592);            // 100,663,296 B
    f16*   msaT = (f16*)(ws + 301989888);            // 100,663,296 B
    f16*   attn = (f16*)(ws + 402653184);            //   1,048,576 B
    f16*   Wq16 = (f16*)(ws + 403701760);            //   1,572,864 B
    f16*   Wo16 = (f16*)(ws + 405274624);            //     524,288 B
    float* logP = out;                               // d_out as scratch (67 MB of 201 MB);
                                                     // k_out_ln overwrites d_out last
    f16*   attn_out = qk;                            // alias: q/k dead after k_logits

    k_prep<<<dim3(3072), dim3(256), 0, stream>>>(Wqkv, Wout, Wq16, Wo16);
    k_cast<<<dim3(24576), dim3(256), 0, stream>>>(msa, msaT);
    k_qkv<<<dim3(9216), dim3(512), 0, stream>>>(msaT, Wq16, bqkv, qk, vT);
    k_logits<<<dim3(1024), dim3(512), 0, stream>>>(qk, logP);
    k_softmax<<<dim3(2048), dim3(256), 0, stream>>>(logP, mask, attn);
    k_pv<<<dim3(3072), dim3(256), 0, stream>>>(attn, vT, attn_out);
    k_out_ln<<<dim3(1536), dim3(512), 0, stream>>>(attn_out, Wo16, bout, msaT, gamma, beta, out);
}